// Round 9
// baseline (369.896 us; speedup 1.0000x reference)
//
#include <hip/hip_runtime.h>
#include <math.h>

#define N_NODES 50000
#define N_EDGES 1600000
#define IN_CH 32
#define HID 64

// ---------------- pipeline (8 dispatches, zero global atomics) -------------
// hist -> scan(3) -> partition(both dirs) -> bindeg(both) -> fgather(both) -> dense
// Bins: 128 dst-nodes (bin = dst>>7), NBIN=391 per dir. Binned entry is ONE
// int: (dstLocal<<21)|edge_id  (eid<2^21, dstLocal<2^7); src and w are
// re-fetched from ei/ew by edge_id inside bindeg/fgather (L2-hot).
// fgather does the per-bin exact sort IN LDS (using bindeg's saved counts)
// and immediately gathers -- the global pair buffers are gone.
#define NBIN 391
#define BIN_SHIFT 7
#define CHUNK 4096
#define NCHK ((N_EDGES + CHUNK - 1) / CHUNK)   // 391
#define CNTG_N (2 * NBIN * NCHK)               // 305762
#define CNTG_N4 ((CNTG_N + 3) / 4)             // 76441 (tail 2 ints are pad)
#define SCAN_BLOCKS ((CNTG_N4 + 1023) / 1024)  // 75
#define EID_MASK 0x1FFFFF
#define FG_CAP 4608   // bin edge capacity: mean 4092 + 8 sigma (Binomial)

// ---------------- workspace layout (int element offsets into d_ws)
// Every region is fully written by its producer -> NO zero pass anywhere.
#define WS_RDEG_OUT 0          // 50000 f (row-degree reciprocals, from dir1 bins)
#define WS_RDEG_IN  50000      // 50000 f (col-degree reciprocals, from dir0 bins)
#define WS_CNTG     100000     // 305764 i ((dir,bin,chunk) counts; scanned in place)
#define WS_BLKSUM   405764     // 96 i
#define WS_BINCNT   405860     // 100096 i (782 bins x 128 per-node counts)
#define WS_BINNED   505956     // 3200000 i (dir0 then dir1 lists)
#define WS_TXO      3705956    // 1600000 f
#define WS_TXI      5305956    // 1600000 f
#define WS_END      6905956    // 27.6 MB (well under proven 40 MB)

// 1. per-chunk coarse histograms, both dirs (LDS atomics; fully writes cntG)
__global__ __launch_bounds__(512) void hist_kernel(const int* __restrict__ ei,
                                                   int* __restrict__ cntG) {
    __shared__ int h[2 * NBIN];
    int tid = threadIdx.x;
    for (int i = tid; i < 2 * NBIN; i += 512) h[i] = 0;
    __syncthreads();
    int e0 = blockIdx.x * CHUNK;
    int e1 = min(e0 + CHUNK, N_EDGES);
    for (int e = e0 + tid; e < e1; e += 512) {
        int r = ei[e];
        int c = ei[N_EDGES + e];
        atomicAdd(&h[c >> BIN_SHIFT], 1);           // dir0: group by col
        atomicAdd(&h[NBIN + (r >> BIN_SHIFT)], 1);  // dir1: group by row
    }
    __syncthreads();
    for (int i = tid; i < 2 * NBIN; i += 512) cntG[i * NCHK + blockIdx.x] = h[i];
}

// ---- 3-phase exclusive scan over cntG (pad tail garbage only affects pad) ----
__global__ __launch_bounds__(256) void scan_partial_kernel(
    const int4* __restrict__ cnt4, int* __restrict__ blksum, int n4) {
    __shared__ int s[256];
    int t = threadIdx.x;
    int base4 = blockIdx.x * 1024 + t * 4;
    int total = 0;
#pragma unroll
    for (int j = 0; j < 4; ++j) {
        int idx = base4 + j;
        if (idx < n4) {
            int4 v = cnt4[idx];
            total += v.x + v.y + v.z + v.w;
        }
    }
    s[t] = total;
    __syncthreads();
    for (int off = 128; off > 0; off >>= 1) {
        if (t < off) s[t] += s[t + off];
        __syncthreads();
    }
    if (t == 0) blksum[blockIdx.x] = s[0];
}

__global__ __launch_bounds__(256) void scan_blocksum_kernel(int* __restrict__ blksum, int nb) {
    __shared__ int s[256];
    int t = threadIdx.x;
    int v = (t < nb) ? blksum[t] : 0;
    s[t] = v;
    __syncthreads();
    for (int off = 1; off < 256; off <<= 1) {
        int u = (t >= off) ? s[t - off] : 0;
        __syncthreads();
        s[t] += u;
        __syncthreads();
    }
    if (t < nb) blksum[t] = s[t] - v;  // exclusive
}

__global__ __launch_bounds__(256) void scan_final_kernel(
    int4* __restrict__ cnt4, const int* __restrict__ blksum, int n4) {
    __shared__ int s[256];
    int t = threadIdx.x;
    int base4 = blockIdx.x * 1024 + t * 4;
    int4 vals[4];
    int total = 0;
#pragma unroll
    for (int j = 0; j < 4; ++j) {
        int idx = base4 + j;
        vals[j] = (idx < n4) ? cnt4[idx] : make_int4(0, 0, 0, 0);
        total += vals[j].x + vals[j].y + vals[j].z + vals[j].w;
    }
    s[t] = total;
    __syncthreads();
    for (int off = 1; off < 256; off <<= 1) {
        int u = (t >= off) ? s[t - off] : 0;
        __syncthreads();
        s[t] += u;
        __syncthreads();
    }
    int run = blksum[blockIdx.x] + s[t] - total;
#pragma unroll
    for (int j = 0; j < 4; ++j) {
        int idx = base4 + j;
        int4 v = vals[j];
        int4 o;
        o.x = run; run += v.x;
        o.y = run; run += v.y;
        o.z = run; run += v.z;
        o.w = run; run += v.w;
        if (idx < n4) cnt4[idx] = o;
    }
}

// 3. coarse partition, BOTH dirs in one read of ei (no ew needed: payload=eid)
__global__ __launch_bounds__(512) void partition_kernel(
    const int* __restrict__ ei, const int* __restrict__ cntG,
    int* __restrict__ binned) {
    __shared__ int cur[2 * NBIN];
    int tid = threadIdx.x;
    for (int i = tid; i < 2 * NBIN; i += 512) cur[i] = cntG[i * NCHK + blockIdx.x];
    __syncthreads();
    int e0 = blockIdx.x * CHUNK;
    int e1 = min(e0 + CHUNK, N_EDGES);
    for (int e = e0 + tid; e < e1; e += 512) {
        int r = ei[e];
        int c = ei[N_EDGES + e];
        int p = atomicAdd(&cur[c >> BIN_SHIFT], 1);          // LDS atomic
        binned[p] = ((c & 127) << 21) | e;
        int q = atomicAdd(&cur[NBIN + (r >> BIN_SHIFT)], 1);
        binned[q] = ((r & 127) << 21) | e;
    }
}

// helper: bin range from scanned cntG
__device__ __forceinline__ void bin_range(const int* cntG, int b, int& lo, int& hi) {
    lo = cntG[b * NCHK];
    hi = (b + 1 < 2 * NBIN) ? cntG[(b + 1) * NCHK] : 2 * N_EDGES;
}

// 4. per-bin degrees + per-node counts (both dirs, one launch).
// dir0 bins (grouped by col) -> deg_in ; dir1 -> deg_out. Also saves the
// 128-entry node histogram so fgather can skip its own counting pass.
__global__ __launch_bounds__(512) void bindeg_kernel(
    const float* __restrict__ ew, const int* __restrict__ cntG,
    const int* __restrict__ binned, int* __restrict__ binCnt,
    float* __restrict__ ws_f) {
    __shared__ float wsum[128];
    __shared__ int cnt[128];
    int tid = threadIdx.x;
    int b = blockIdx.x;
    int dir = (b >= NBIN) ? 1 : 0;
    if (tid < 128) { wsum[tid] = 0.f; cnt[tid] = 0; }
    __syncthreads();
    int lo, hi;
    bin_range(cntG, b, lo, hi);
    for (int p = lo + tid; p < hi; p += 512) {
        int v = binned[p];
        int d = v >> 21;
        atomicAdd(&cnt[d], 1);
        atomicAdd(&wsum[d], ew[v & EID_MASK]);  // LDS float atomic
    }
    __syncthreads();
    if (tid < 128) {
        binCnt[b * 128 + tid] = cnt[tid];
        int node = (b - dir * NBIN) * 128 + tid;
        if (node < N_NODES) {
            float s = wsum[tid];
            float* rdeg = ws_f + (dir == 0 ? WS_RDEG_IN : WS_RDEG_OUT);
            rdeg[node] = (s != 0.f) ? (1.f / s) : 0.f;
        }
    }
}

// 5. fused in-LDS binsort + gather (both dirs, one launch).
//   A: LDS scan of bindeg's 128 counts -> per-node start offsets
//   B: scatter bin edges into the LDS sorted list (rank = LDS atomic)
//   C: 64 groups x 8 lanes walk per-node lists, acc in registers, write Tx
__global__ __launch_bounds__(512) void fgather_kernel(
    const int* __restrict__ ei, const float* __restrict__ ew,
    const float4* __restrict__ x4, const int* __restrict__ cntG,
    const int* __restrict__ binCnt, const int* __restrict__ binned,
    float* __restrict__ ws_f) {
    __shared__ int s_edge[FG_CAP];   // 18 KB
    __shared__ int s_off[129];
    __shared__ int s_cur[128];
    __shared__ int sc[128];
    int tid = threadIdx.x;
    int b = blockIdx.x;
    int dir = (b >= NBIN) ? 1 : 0;

    // A: exclusive scan of the 128 node counts
    int v = (tid < 128) ? binCnt[b * 128 + tid] : 0;
    if (tid < 128) sc[tid] = v;
    __syncthreads();
    for (int off = 1; off < 128; off <<= 1) {
        int u = (tid < 128 && tid >= off) ? sc[tid - off] : 0;
        __syncthreads();
        if (tid < 128) sc[tid] += u;
        __syncthreads();
    }
    if (tid < 128) {
        s_off[tid] = sc[tid] - v;
        s_cur[tid] = sc[tid] - v;
    }
    if (tid == 127) s_off[128] = sc[127];
    __syncthreads();

    // B: scatter into LDS sorted order
    int lo, hi;
    bin_range(cntG, b, lo, hi);
    int n_e = hi - lo;
    for (int p = tid; p < n_e; p += 512) {
        int ev = binned[lo + p];
        int rk = atomicAdd(&s_cur[ev >> 21], 1);
        if (rk < FG_CAP) s_edge[rk] = ev;
    }
    __syncthreads();

    // C: register-accumulating gather
    const float* rdeg = ws_f + (dir == 0 ? WS_RDEG_OUT : WS_RDEG_IN);
    const int* srcArr = ei + (dir == 0 ? 0 : N_EDGES);
    float4* outp = (float4*)(ws_f + (dir == 0 ? WS_TXO : WS_TXI));
    int lane = tid & 7;
    int nodeBase = (b - dir * NBIN) * 128;
#pragma unroll
    for (int it = 0; it < 2; ++it) {
        int nl = it * 64 + (tid >> 3);
        int p = s_off[nl], end = s_off[nl + 1];
        float4 acc = make_float4(0.f, 0.f, 0.f, 0.f);
        for (; p + 1 < end; p += 2) {  // 2-way unroll for load ILP
            int v0 = s_edge[p], v1 = s_edge[p + 1];
            int e0 = v0 & EID_MASK, e1 = v1 & EID_MASK;
            int s0 = srcArr[e0], s1 = srcArr[e1];
            float c0 = ew[e0] * rdeg[s0];
            float c1 = ew[e1] * rdeg[s1];
            float4 a = x4[s0 * 8 + lane];
            float4 bb = x4[s1 * 8 + lane];
            acc.x += c0 * a.x + c1 * bb.x;
            acc.y += c0 * a.y + c1 * bb.y;
            acc.z += c0 * a.z + c1 * bb.z;
            acc.w += c0 * a.w + c1 * bb.w;
        }
        if (p < end) {
            int v0 = s_edge[p];
            int e0 = v0 & EID_MASK;
            int s0 = srcArr[e0];
            float c0 = ew[e0] * rdeg[s0];
            float4 a = x4[s0 * 8 + lane];
            acc.x += c0 * a.x;
            acc.y += c0 * a.y;
            acc.z += c0 * a.z;
            acc.w += c0 * a.w;
        }
        int node = nodeBase + nl;
        if (node < N_NODES) outp[node * 8 + lane] = acc;
    }
}

// 6. Fused dense epilogue. Round-9 change: kq loop unrolled x8 so LDS reads
// use compile-time immediate offsets (kills per-read address VALU).
#define DN_GROUP 64
#define DN_BLOCKS ((N_NODES + DN_GROUP - 1) / DN_GROUP)  // 782
#define WT_STRIDE 100
__global__ __launch_bounds__(256) void dense_kernel(
    const float4* __restrict__ x4,
    const float4* __restrict__ txo4, const float4* __restrict__ txi4,
    const float* __restrict__ Wz, const float* __restrict__ bz,
    const float* __restrict__ Wh, const float* __restrict__ bh,
    const float* __restrict__ Wlin, const float* __restrict__ blin,
    float* __restrict__ out) {
    __shared__ float s_wzT[64 * WT_STRIDE];
    __shared__ float s_whT[64 * WT_STRIDE];
    __shared__ float s_in[DN_GROUP * 96];

    int tid = threadIdx.x;
    int o = tid & 63, w = tid >> 6;
    float bzo = bz[o], bho = bh[o], wlo = Wlin[o], bl = blin[0];

    for (int idx = tid; idx < 96 * 64; idx += 256) {
        int k = idx >> 6, oo = idx & 63;
        int slab = k >> 5, c = k & 31;
        float wz, wh;
        if (slab == 0) {
            wz = Wz[c * 64 + oo] + Wz[(2 * 96 + c) * 64 + oo];
            wh = Wh[c * 64 + oo] + Wh[(2 * 96 + c) * 64 + oo];
        } else if (slab == 1) {
            wz = Wz[(96 + c) * 64 + oo];
            wh = Wh[(96 + c) * 64 + oo];
        } else {
            wz = Wz[(3 * 96 + c) * 64 + oo];
            wh = Wh[(3 * 96 + c) * 64 + oo];
        }
        s_wzT[oo * WT_STRIDE + k] = wz;
        s_whT[oo * WT_STRIDE + k] = wh;
    }

    int node0 = blockIdx.x * DN_GROUP;
    for (int idx = tid; idx < DN_GROUP * 24; idx += 256) {
        int nl = idx / 24, q = idx - nl * 24;
        int node = node0 + nl;
        float4 v = make_float4(0.f, 0.f, 0.f, 0.f);
        if (node < N_NODES) {
            if (q < 8)       v = x4[node * 8 + q];
            else if (q < 16) v = txo4[node * 8 + (q - 8)];
            else             v = txi4[node * 8 + (q - 16)];
        }
        *(float4*)&s_in[nl * 96 + q * 4] = v;
    }
    __syncthreads();

    float accz[16], acch[16];
#pragma unroll
    for (int n = 0; n < 16; ++n) { accz[n] = bzo; acch[n] = bho; }
    const float* wzp = &s_wzT[o * WT_STRIDE];
    const float* whp = &s_whT[o * WT_STRIDE];
    const float* inp = &s_in[w * 16 * 96];

#pragma unroll 8
    for (int kq = 0; kq < 24; ++kq) {
        float4 wz = *(const float4*)&wzp[kq * 4];
        float4 wh = *(const float4*)&whp[kq * 4];
#pragma unroll
        for (int n = 0; n < 16; ++n) {
            float4 xk = *(const float4*)&inp[n * 96 + kq * 4];
            accz[n] += xk.x * wz.x + xk.y * wz.y + xk.z * wz.z + xk.w * wz.w;
            acch[n] += xk.x * wh.x + xk.y * wh.y + xk.z * wh.z + xk.w * wh.w;
        }
    }

#pragma unroll
    for (int n = 0; n < 16; ++n) {
        float z = 1.f / (1.f + __expf(-accz[n]));
        float ht = 1.f - 2.f / (__expf(2.f * acch[n]) + 1.f);
        float rr = fmaxf((1.f - z) * ht, 0.f) * wlo;
#pragma unroll
        for (int off = 32; off > 0; off >>= 1)
            rr += __shfl_down(rr, off, 64);
        if (o == 0) {
            int node = node0 + w * 16 + n;
            if (node < N_NODES) out[node] = rr + bl;
        }
    }
}

extern "C" void kernel_launch(void* const* d_in, const int* in_sizes, int n_in,
                              void* d_out, int out_size, void* d_ws, size_t ws_size,
                              hipStream_t stream) {
    const float* x = (const float*)d_in[0];
    const int* ei = (const int*)d_in[1];
    const float* ew = (const float*)d_in[2];
    const float* Wz = (const float*)d_in[3];
    const float* bz = (const float*)d_in[4];
    // d_in[5]=Wr, d_in[6]=br dead: H0==0 makes the reset gate a no-op
    const float* Wh = (const float*)d_in[7];
    const float* bh = (const float*)d_in[8];
    const float* Wlin = (const float*)d_in[9];
    const float* blin = (const float*)d_in[10];
    float* out = (float*)d_out;
    float* wf = (float*)d_ws;
    int* wi = (int*)d_ws;

    // 1. coarse per-chunk histograms, both dirs
    hist_kernel<<<NCHK, 512, 0, stream>>>(ei, wi + WS_CNTG);
    // 2. exclusive scan of the (dir,bin,chunk) count matrix
    scan_partial_kernel<<<SCAN_BLOCKS, 256, 0, stream>>>(
        (const int4*)(wi + WS_CNTG), wi + WS_BLKSUM, CNTG_N4);
    scan_blocksum_kernel<<<1, 256, 0, stream>>>(wi + WS_BLKSUM, SCAN_BLOCKS);
    scan_final_kernel<<<SCAN_BLOCKS, 256, 0, stream>>>(
        (int4*)(wi + WS_CNTG), wi + WS_BLKSUM, CNTG_N4);
    // 3. partition both dirs in one pass (payload = dstLocal<<21 | eid)
    partition_kernel<<<NCHK, 512, 0, stream>>>(ei, wi + WS_CNTG, wi + WS_BINNED);
    // 4. per-bin degrees + saved node counts (both dirs)
    bindeg_kernel<<<2 * NBIN, 512, 0, stream>>>(
        ew, wi + WS_CNTG, wi + WS_BINNED, wi + WS_BINCNT, wf);
    // 5. fused in-LDS binsort + register gather (both dirs) -> Tx_o, Tx_i
    fgather_kernel<<<2 * NBIN, 512, 0, stream>>>(
        ei, ew, (const float4*)x, wi + WS_CNTG, wi + WS_BINCNT, wi + WS_BINNED, wf);
    // 6. fused dense epilogue
    dense_kernel<<<DN_BLOCKS, 256, 0, stream>>>(
        (const float4*)x, (const float4*)(wf + WS_TXO), (const float4*)(wf + WS_TXI),
        Wz, bz, Wh, bh, Wlin, blin, out);
}

// Round 10
// 283.130 us; speedup vs baseline: 1.3065x; 1.3065x over previous
//
#include <hip/hip_runtime.h>
#include <math.h>

#define N_NODES 50000
#define N_EDGES 1600000
#define IN_CH 32
#define HID 64

// ---------------- pipeline (9 dispatches, zero global atomics) -------------
// hist -> scan(3) -> partition(both dirs) -> bindeg(both) -> fgather(dir0)
//   -> fgather(dir1) -> dense
// Bins: 64 dst-nodes (bin = dst>>6), NBIN=782 per dir. Binned payload is an
// int2 {(dstLocal<<16)|src, w_bits} -- src and w travel WITH the edge, so
// every pass streams the binned buffer LINEARLY (round-9 lesson: random 4B
// eid re-fetch cost 482 MB of L2-miss traffic; linear 25.6 MB streaming wins).
// fgather does the per-bin exact sort in LDS and gathers immediately.
#define NBIN 782
#define BIN_SHIFT 6
#define CHUNK 4096
#define NCHK ((N_EDGES + CHUNK - 1) / CHUNK)   // 391
#define CNTG_N (2 * NBIN * NCHK)               // 611524 (divisible by 4)
#define CNTG_N4 (CNTG_N / 4)                   // 152881
#define SCAN_BLOCKS ((CNTG_N4 + 1023) / 1024)  // 150
#define FG_CAP 2560   // bin capacity: mean 2046 + ~11 sigma (Binomial)

// ---------------- workspace layout (int element offsets into d_ws)
// Every region fully written by its producer -> no zero pass anywhere.
#define WS_RDEG_OUT 0          // 50000 f (row-degree reciprocals, from dir1 bins)
#define WS_RDEG_IN  50000      // 50000 f (col-degree reciprocals, from dir0 bins)
#define WS_CNTG     100000     // 611524 i ((dir,bin,chunk) counts; scanned in place)
#define WS_BLKSUM   711528     // 256 i
#define WS_BINCNT   711784     // 100096 i (1564 bins x 64 per-node counts)
#define WS_BINNED   811880     // int2[3.2M] = 6400000 i (dir0 half then dir1 half)
#define WS_TXO      7211880    // 1600000 f
#define WS_TXI      811880     // 1600000 f -- ALIASES binned dir0 half (dead by then)
#define WS_END      8811880    // 35.3 MB high-water (< proven 40 MB)

// 1. per-chunk coarse histograms, both dirs (LDS atomics; fully writes cntG)
__global__ __launch_bounds__(512) void hist_kernel(const int* __restrict__ ei,
                                                   int* __restrict__ cntG) {
    __shared__ int h[2 * NBIN];
    int tid = threadIdx.x;
    for (int i = tid; i < 2 * NBIN; i += 512) h[i] = 0;
    __syncthreads();
    int e0 = blockIdx.x * CHUNK;
    int e1 = min(e0 + CHUNK, N_EDGES);
    for (int e = e0 + tid; e < e1; e += 512) {
        int r = ei[e];
        int c = ei[N_EDGES + e];
        atomicAdd(&h[c >> BIN_SHIFT], 1);           // dir0: group by col
        atomicAdd(&h[NBIN + (r >> BIN_SHIFT)], 1);  // dir1: group by row
    }
    __syncthreads();
    for (int i = tid; i < 2 * NBIN; i += 512) cntG[i * NCHK + blockIdx.x] = h[i];
}

// ---- 3-phase exclusive scan over cntG ----
__global__ __launch_bounds__(256) void scan_partial_kernel(
    const int4* __restrict__ cnt4, int* __restrict__ blksum, int n4) {
    __shared__ int s[256];
    int t = threadIdx.x;
    int base4 = blockIdx.x * 1024 + t * 4;
    int total = 0;
#pragma unroll
    for (int j = 0; j < 4; ++j) {
        int idx = base4 + j;
        if (idx < n4) {
            int4 v = cnt4[idx];
            total += v.x + v.y + v.z + v.w;
        }
    }
    s[t] = total;
    __syncthreads();
    for (int off = 128; off > 0; off >>= 1) {
        if (t < off) s[t] += s[t + off];
        __syncthreads();
    }
    if (t == 0) blksum[blockIdx.x] = s[0];
}

__global__ __launch_bounds__(256) void scan_blocksum_kernel(int* __restrict__ blksum, int nb) {
    __shared__ int s[256];
    int t = threadIdx.x;
    int v = (t < nb) ? blksum[t] : 0;
    s[t] = v;
    __syncthreads();
    for (int off = 1; off < 256; off <<= 1) {
        int u = (t >= off) ? s[t - off] : 0;
        __syncthreads();
        s[t] += u;
        __syncthreads();
    }
    if (t < nb) blksum[t] = s[t] - v;  // exclusive
}

__global__ __launch_bounds__(256) void scan_final_kernel(
    int4* __restrict__ cnt4, const int* __restrict__ blksum, int n4) {
    __shared__ int s[256];
    int t = threadIdx.x;
    int base4 = blockIdx.x * 1024 + t * 4;
    int4 vals[4];
    int total = 0;
#pragma unroll
    for (int j = 0; j < 4; ++j) {
        int idx = base4 + j;
        vals[j] = (idx < n4) ? cnt4[idx] : make_int4(0, 0, 0, 0);
        total += vals[j].x + vals[j].y + vals[j].z + vals[j].w;
    }
    s[t] = total;
    __syncthreads();
    for (int off = 1; off < 256; off <<= 1) {
        int u = (t >= off) ? s[t - off] : 0;
        __syncthreads();
        s[t] += u;
        __syncthreads();
    }
    int run = blksum[blockIdx.x] + s[t] - total;
#pragma unroll
    for (int j = 0; j < 4; ++j) {
        int idx = base4 + j;
        int4 v = vals[j];
        int4 o;
        o.x = run; run += v.x;
        o.y = run; run += v.y;
        o.z = run; run += v.z;
        o.w = run; run += v.w;
        if (idx < n4) cnt4[idx] = o;
    }
}

// 3. coarse partition, BOTH dirs in one pass; payload carries src and w
__global__ __launch_bounds__(512) void partition_kernel(
    const int* __restrict__ ei, const float* __restrict__ ew,
    const int* __restrict__ cntG, int2* __restrict__ binned) {
    __shared__ int cur[2 * NBIN];
    int tid = threadIdx.x;
    for (int i = tid; i < 2 * NBIN; i += 512) cur[i] = cntG[i * NCHK + blockIdx.x];
    __syncthreads();
    int e0 = blockIdx.x * CHUNK;
    int e1 = min(e0 + CHUNK, N_EDGES);
    for (int e = e0 + tid; e < e1; e += 512) {
        int r = ei[e];
        int c = ei[N_EDGES + e];
        int wb = __float_as_int(ew[e]);
        int p = atomicAdd(&cur[c >> BIN_SHIFT], 1);          // LDS atomic
        binned[p] = make_int2(((c & 63) << 16) | r, wb);     // src < 65536 OK
        int q = atomicAdd(&cur[NBIN + (r >> BIN_SHIFT)], 1);
        binned[q] = make_int2(((r & 63) << 16) | c, wb);
    }
}

// helper: bin range (int2 positions) from scanned cntG
__device__ __forceinline__ void bin_range(const int* cntG, int b, int& lo, int& hi) {
    lo = cntG[b * NCHK];
    hi = (b + 1 < 2 * NBIN) ? cntG[(b + 1) * NCHK] : 2 * N_EDGES;
}

// 4. per-bin degrees + per-node counts (both dirs, one launch); linear stream.
__global__ __launch_bounds__(512) void bindeg_kernel(
    const int* __restrict__ cntG, const int2* __restrict__ binned,
    int* __restrict__ binCnt, float* __restrict__ ws_f) {
    __shared__ float wsum[64];
    __shared__ int cnt[64];
    int tid = threadIdx.x;
    int b = blockIdx.x;
    int dir = (b >= NBIN) ? 1 : 0;
    if (tid < 64) { wsum[tid] = 0.f; cnt[tid] = 0; }
    __syncthreads();
    int lo, hi;
    bin_range(cntG, b, lo, hi);
    for (int p = lo + tid; p < hi; p += 512) {
        int2 v = binned[p];
        int d = v.x >> 16;
        atomicAdd(&cnt[d], 1);
        atomicAdd(&wsum[d], __int_as_float(v.y));  // LDS float atomic
    }
    __syncthreads();
    if (tid < 64) {
        binCnt[b * 64 + tid] = cnt[tid];
        int node = (b - dir * NBIN) * 64 + tid;
        if (node < N_NODES) {
            float s = wsum[tid];
            float* rdeg = ws_f + (dir == 0 ? WS_RDEG_IN : WS_RDEG_OUT);
            rdeg[node] = (s != 0.f) ? (1.f / s) : 0.f;
        }
    }
}

// 5. fused in-LDS binsort + register gather, one direction per launch.
//   A: LDS scan of the 64 node counts -> per-node start offsets
//   B: stream bin edges into LDS sorted order (rank = LDS atomic)
//   C: 64 groups x 8 lanes walk per-node lists, acc in registers, write Tx
__global__ __launch_bounds__(512) void fgather_kernel(
    const float4* __restrict__ x4, const int* __restrict__ cntG,
    const int* __restrict__ binCnt, const int2* __restrict__ binned,
    float* __restrict__ ws_f, int dir) {
    __shared__ int2 s_edge[FG_CAP];  // 20.5 KB
    __shared__ int s_off[65];
    __shared__ int s_cur[64];
    __shared__ int sc[64];
    int tid = threadIdx.x;
    int b = dir * NBIN + blockIdx.x;

    // A: exclusive scan of 64 counts
    int v = (tid < 64) ? binCnt[b * 64 + tid] : 0;
    if (tid < 64) sc[tid] = v;
    __syncthreads();
    for (int off = 1; off < 64; off <<= 1) {
        int u = (tid < 64 && tid >= off) ? sc[tid - off] : 0;
        __syncthreads();
        if (tid < 64) sc[tid] += u;
        __syncthreads();
    }
    if (tid < 64) {
        s_off[tid] = sc[tid] - v;
        s_cur[tid] = sc[tid] - v;
    }
    if (tid == 63) s_off[64] = sc[63];
    __syncthreads();

    // B: scatter into LDS sorted order (linear read of binned)
    int lo, hi;
    bin_range(cntG, b, lo, hi);
    int n_e = hi - lo;
    for (int p = tid; p < n_e; p += 512) {
        int2 ev = binned[lo + p];
        int rk = atomicAdd(&s_cur[ev.x >> 16], 1);
        if (rk < FG_CAP) s_edge[rk] = ev;
    }
    __syncthreads();

    // C: register-accumulating gather; coef = w * rdeg[src]
    const float* rdeg = ws_f + (dir == 0 ? WS_RDEG_OUT : WS_RDEG_IN);
    float4* outp = (float4*)(ws_f + (dir == 0 ? WS_TXO : WS_TXI));
    int lane = tid & 7;
    int nl = tid >> 3;  // 64 groups, exactly one per node
    int p = s_off[nl], end = s_off[nl + 1];
    float4 acc = make_float4(0.f, 0.f, 0.f, 0.f);
    for (; p + 1 < end; p += 2) {  // 2-way unroll for load ILP
        int2 v0 = s_edge[p], v1 = s_edge[p + 1];
        int s0 = v0.x & 0xffff, s1 = v1.x & 0xffff;
        float c0 = __int_as_float(v0.y) * rdeg[s0];
        float c1 = __int_as_float(v1.y) * rdeg[s1];
        float4 a = x4[s0 * 8 + lane];
        float4 bb = x4[s1 * 8 + lane];
        acc.x += c0 * a.x + c1 * bb.x;
        acc.y += c0 * a.y + c1 * bb.y;
        acc.z += c0 * a.z + c1 * bb.z;
        acc.w += c0 * a.w + c1 * bb.w;
    }
    if (p < end) {
        int2 v0 = s_edge[p];
        int s0 = v0.x & 0xffff;
        float c0 = __int_as_float(v0.y) * rdeg[s0];
        float4 a = x4[s0 * 8 + lane];
        acc.x += c0 * a.x;
        acc.y += c0 * a.y;
        acc.z += c0 * a.z;
        acc.w += c0 * a.w;
    }
    int node = blockIdx.x * 64 + nl;
    if (node < N_NODES) outp[node * 8 + lane] = acc;
}

// 6. Fused dense epilogue (weights transposed in LDS, 16-node register batch,
// kq loop unrolled x8 for immediate-offset LDS reads).
#define DN_GROUP 64
#define DN_BLOCKS ((N_NODES + DN_GROUP - 1) / DN_GROUP)  // 782
#define WT_STRIDE 100
__global__ __launch_bounds__(256) void dense_kernel(
    const float4* __restrict__ x4,
    const float4* __restrict__ txo4, const float4* __restrict__ txi4,
    const float* __restrict__ Wz, const float* __restrict__ bz,
    const float* __restrict__ Wh, const float* __restrict__ bh,
    const float* __restrict__ Wlin, const float* __restrict__ blin,
    float* __restrict__ out) {
    __shared__ float s_wzT[64 * WT_STRIDE];
    __shared__ float s_whT[64 * WT_STRIDE];
    __shared__ float s_in[DN_GROUP * 96];

    int tid = threadIdx.x;
    int o = tid & 63, w = tid >> 6;
    float bzo = bz[o], bho = bh[o], wlo = Wlin[o], bl = blin[0];

    for (int idx = tid; idx < 96 * 64; idx += 256) {
        int k = idx >> 6, oo = idx & 63;
        int slab = k >> 5, c = k & 31;
        float wz, wh;
        if (slab == 0) {
            wz = Wz[c * 64 + oo] + Wz[(2 * 96 + c) * 64 + oo];
            wh = Wh[c * 64 + oo] + Wh[(2 * 96 + c) * 64 + oo];
        } else if (slab == 1) {
            wz = Wz[(96 + c) * 64 + oo];
            wh = Wh[(96 + c) * 64 + oo];
        } else {
            wz = Wz[(3 * 96 + c) * 64 + oo];
            wh = Wh[(3 * 96 + c) * 64 + oo];
        }
        s_wzT[oo * WT_STRIDE + k] = wz;
        s_whT[oo * WT_STRIDE + k] = wh;
    }

    int node0 = blockIdx.x * DN_GROUP;
    for (int idx = tid; idx < DN_GROUP * 24; idx += 256) {
        int nl = idx / 24, q = idx - nl * 24;
        int node = node0 + nl;
        float4 v = make_float4(0.f, 0.f, 0.f, 0.f);
        if (node < N_NODES) {
            if (q < 8)       v = x4[node * 8 + q];
            else if (q < 16) v = txo4[node * 8 + (q - 8)];
            else             v = txi4[node * 8 + (q - 16)];
        }
        *(float4*)&s_in[nl * 96 + q * 4] = v;
    }
    __syncthreads();

    float accz[16], acch[16];
#pragma unroll
    for (int n = 0; n < 16; ++n) { accz[n] = bzo; acch[n] = bho; }
    const float* wzp = &s_wzT[o * WT_STRIDE];
    const float* whp = &s_whT[o * WT_STRIDE];
    const float* inp = &s_in[w * 16 * 96];

#pragma unroll 8
    for (int kq = 0; kq < 24; ++kq) {
        float4 wz = *(const float4*)&wzp[kq * 4];
        float4 wh = *(const float4*)&whp[kq * 4];
#pragma unroll
        for (int n = 0; n < 16; ++n) {
            float4 xk = *(const float4*)&inp[n * 96 + kq * 4];
            accz[n] += xk.x * wz.x + xk.y * wz.y + xk.z * wz.z + xk.w * wz.w;
            acch[n] += xk.x * wh.x + xk.y * wh.y + xk.z * wh.z + xk.w * wh.w;
        }
    }

#pragma unroll
    for (int n = 0; n < 16; ++n) {
        float z = 1.f / (1.f + __expf(-accz[n]));
        float ht = 1.f - 2.f / (__expf(2.f * acch[n]) + 1.f);
        float rr = fmaxf((1.f - z) * ht, 0.f) * wlo;
#pragma unroll
        for (int off = 32; off > 0; off >>= 1)
            rr += __shfl_down(rr, off, 64);
        if (o == 0) {
            int node = node0 + w * 16 + n;
            if (node < N_NODES) out[node] = rr + bl;
        }
    }
}

extern "C" void kernel_launch(void* const* d_in, const int* in_sizes, int n_in,
                              void* d_out, int out_size, void* d_ws, size_t ws_size,
                              hipStream_t stream) {
    const float* x = (const float*)d_in[0];
    const int* ei = (const int*)d_in[1];
    const float* ew = (const float*)d_in[2];
    const float* Wz = (const float*)d_in[3];
    const float* bz = (const float*)d_in[4];
    // d_in[5]=Wr, d_in[6]=br dead: H0==0 makes the reset gate a no-op
    const float* Wh = (const float*)d_in[7];
    const float* bh = (const float*)d_in[8];
    const float* Wlin = (const float*)d_in[9];
    const float* blin = (const float*)d_in[10];
    float* out = (float*)d_out;
    float* wf = (float*)d_ws;
    int* wi = (int*)d_ws;
    int2* binned = (int2*)(wi + WS_BINNED);

    // 1. coarse per-chunk histograms, both dirs
    hist_kernel<<<NCHK, 512, 0, stream>>>(ei, wi + WS_CNTG);
    // 2. exclusive scan of the (dir,bin,chunk) count matrix
    scan_partial_kernel<<<SCAN_BLOCKS, 256, 0, stream>>>(
        (const int4*)(wi + WS_CNTG), wi + WS_BLKSUM, CNTG_N4);
    scan_blocksum_kernel<<<1, 256, 0, stream>>>(wi + WS_BLKSUM, SCAN_BLOCKS);
    scan_final_kernel<<<SCAN_BLOCKS, 256, 0, stream>>>(
        (int4*)(wi + WS_CNTG), wi + WS_BLKSUM, CNTG_N4);
    // 3. partition both dirs (payload int2 = {dstLocal<<16|src, w})
    partition_kernel<<<NCHK, 512, 0, stream>>>(ei, ew, wi + WS_CNTG, binned);
    // 4. per-bin degrees + saved node counts (both dirs, linear stream)
    bindeg_kernel<<<2 * NBIN, 512, 0, stream>>>(
        wi + WS_CNTG, binned, wi + WS_BINCNT, wf);
    // 5a. fused binsort+gather dir0 -> Tx_o
    fgather_kernel<<<NBIN, 512, 0, stream>>>(
        (const float4*)x, wi + WS_CNTG, wi + WS_BINCNT, binned, wf, 0);
    // 5b. fused binsort+gather dir1 -> Tx_i (writes over dead dir0 binned half)
    fgather_kernel<<<NBIN, 512, 0, stream>>>(
        (const float4*)x, wi + WS_CNTG, wi + WS_BINCNT, binned, wf, 1);
    // 6. fused dense epilogue
    dense_kernel<<<DN_BLOCKS, 256, 0, stream>>>(
        (const float4*)x, (const float4*)(wf + WS_TXO), (const float4*)(wf + WS_TXI),
        Wz, bz, Wh, bh, Wlin, blin, out);
}

// Round 11
// 236.024 us; speedup vs baseline: 1.5672x; 1.1996x over previous
//
#include <hip/hip_runtime.h>
#include <math.h>

#define N_NODES 50000
#define N_EDGES 1600000
#define IN_CH 32
#define HID 64

// ---------------- pipeline (10 dispatches, zero global atomics) ------------
// wprep -> hist -> scan(3) -> partition -> bindeg -> fgather(dir0)
//   -> fgather(dir1) -> dense(MFMA)
// Bins: 64 dst-nodes, NBIN=782/dir. Binned payload int2 {(dstLocal<<16)|src,
// w_bits} -- src/w travel WITH the edge; all passes stream binned LINEARLY.
// Round-11 change: dense rewritten as bf16 MFMA (16x16x32), weights
// pre-swizzled into B-fragment order by wprep. fp32 accumulate.
#define NBIN 782
#define BIN_SHIFT 6
#define CHUNK 4096
#define NCHK ((N_EDGES + CHUNK - 1) / CHUNK)   // 391
#define CNTG_N (2 * NBIN * NCHK)               // 611524
#define CNTG_N4 (CNTG_N / 4)                   // 152881
#define SCAN_BLOCKS ((CNTG_N4 + 1023) / 1024)  // 150
#define FG_CAP 2560   // bin capacity: mean 2046 + ~11 sigma (Binomial)

// ---------------- workspace layout (int element offsets into d_ws)
#define WS_RDEG_OUT 0          // 50000 f (row-degree reciprocals, from dir1 bins)
#define WS_RDEG_IN  50000      // 50000 f (col-degree reciprocals, from dir0 bins)
#define WS_CNTG     100000     // 611524 i ((dir,bin,chunk) counts; scanned in place)
#define WS_BLKSUM   711528     // 256 i
#define WS_WBF      711784     // 6144 i = 12288 ushort (bf16 weights, B-frag order)
#define WS_BINCNT   717928     // 100096 i (1564 bins x 64 per-node counts)
#define WS_BINNED   818024     // int2[3.2M] = 6400000 i (dir0 half then dir1 half)
#define WS_TXO      7218024    // 1600000 f
#define WS_TXI      818024     // 1600000 f -- ALIASES binned dir0 half (dead by then)
#define WS_END      8818024    // 35.3 MB high-water (< proven 40 MB)

typedef __attribute__((ext_vector_type(8))) short bf16x8;
typedef __attribute__((ext_vector_type(4))) float f32x4;

__device__ __forceinline__ unsigned short f2bf(float f) {  // RNE fp32 -> bf16
    unsigned int u = __float_as_uint(f);
    return (unsigned short)((u + 0x7fffu + ((u >> 16) & 1u)) >> 16);
}

// 0. weight prep: combine diffusion slabs, bf16-convert, store in the EXACT
// B-fragment order used by dense: idx = ((kk*8+bn)*64+lane)*8 + j holds
// Bmat[k=kk*32+(lane>>4)*8+j][n=bn*16+(lane&15)], Bmat = [Wz_eff | Wh_eff].
__global__ __launch_bounds__(256) void wprep_kernel(
    const float* __restrict__ Wz, const float* __restrict__ Wh,
    unsigned short* __restrict__ wbf) {
    int idx = blockIdx.x * 256 + threadIdx.x;
    if (idx >= 12288) return;
    int j = idx & 7, ln = (idx >> 3) & 63, bn = (idx >> 9) & 7, kk = idx >> 12;
    int k = kk * 32 + (ln >> 4) * 8 + j;
    int n = bn * 16 + (ln & 15);
    int slab = k >> 5, c = k & 31;
    const float* W = (n < 64) ? Wz : Wh;
    int o = n & 63;
    float v;
    if (slab == 0)      v = W[c * 64 + o] + W[(2 * 96 + c) * 64 + o];
    else if (slab == 1) v = W[(96 + c) * 64 + o];
    else                v = W[(3 * 96 + c) * 64 + o];
    wbf[idx] = f2bf(v);
}

// 1. per-chunk coarse histograms, both dirs (LDS atomics; fully writes cntG)
__global__ __launch_bounds__(512) void hist_kernel(const int* __restrict__ ei,
                                                   int* __restrict__ cntG) {
    __shared__ int h[2 * NBIN];
    int tid = threadIdx.x;
    for (int i = tid; i < 2 * NBIN; i += 512) h[i] = 0;
    __syncthreads();
    int e0 = blockIdx.x * CHUNK;
    int e1 = min(e0 + CHUNK, N_EDGES);
    for (int e = e0 + tid; e < e1; e += 512) {
        int r = ei[e];
        int c = ei[N_EDGES + e];
        atomicAdd(&h[c >> BIN_SHIFT], 1);
        atomicAdd(&h[NBIN + (r >> BIN_SHIFT)], 1);
    }
    __syncthreads();
    for (int i = tid; i < 2 * NBIN; i += 512) cntG[i * NCHK + blockIdx.x] = h[i];
}

// ---- 3-phase exclusive scan over cntG ----
__global__ __launch_bounds__(256) void scan_partial_kernel(
    const int4* __restrict__ cnt4, int* __restrict__ blksum, int n4) {
    __shared__ int s[256];
    int t = threadIdx.x;
    int base4 = blockIdx.x * 1024 + t * 4;
    int total = 0;
#pragma unroll
    for (int j = 0; j < 4; ++j) {
        int idx = base4 + j;
        if (idx < n4) {
            int4 v = cnt4[idx];
            total += v.x + v.y + v.z + v.w;
        }
    }
    s[t] = total;
    __syncthreads();
    for (int off = 128; off > 0; off >>= 1) {
        if (t < off) s[t] += s[t + off];
        __syncthreads();
    }
    if (t == 0) blksum[blockIdx.x] = s[0];
}

__global__ __launch_bounds__(256) void scan_blocksum_kernel(int* __restrict__ blksum, int nb) {
    __shared__ int s[256];
    int t = threadIdx.x;
    int v = (t < nb) ? blksum[t] : 0;
    s[t] = v;
    __syncthreads();
    for (int off = 1; off < 256; off <<= 1) {
        int u = (t >= off) ? s[t - off] : 0;
        __syncthreads();
        s[t] += u;
        __syncthreads();
    }
    if (t < nb) blksum[t] = s[t] - v;  // exclusive
}

__global__ __launch_bounds__(256) void scan_final_kernel(
    int4* __restrict__ cnt4, const int* __restrict__ blksum, int n4) {
    __shared__ int s[256];
    int t = threadIdx.x;
    int base4 = blockIdx.x * 1024 + t * 4;
    int4 vals[4];
    int total = 0;
#pragma unroll
    for (int j = 0; j < 4; ++j) {
        int idx = base4 + j;
        vals[j] = (idx < n4) ? cnt4[idx] : make_int4(0, 0, 0, 0);
        total += vals[j].x + vals[j].y + vals[j].z + vals[j].w;
    }
    s[t] = total;
    __syncthreads();
    for (int off = 1; off < 256; off <<= 1) {
        int u = (t >= off) ? s[t - off] : 0;
        __syncthreads();
        s[t] += u;
        __syncthreads();
    }
    int run = blksum[blockIdx.x] + s[t] - total;
#pragma unroll
    for (int j = 0; j < 4; ++j) {
        int idx = base4 + j;
        int4 v = vals[j];
        int4 o;
        o.x = run; run += v.x;
        o.y = run; run += v.y;
        o.z = run; run += v.z;
        o.w = run; run += v.w;
        if (idx < n4) cnt4[idx] = o;
    }
}

// 3. coarse partition, BOTH dirs in one pass; payload carries src and w
__global__ __launch_bounds__(512) void partition_kernel(
    const int* __restrict__ ei, const float* __restrict__ ew,
    const int* __restrict__ cntG, int2* __restrict__ binned) {
    __shared__ int cur[2 * NBIN];
    int tid = threadIdx.x;
    for (int i = tid; i < 2 * NBIN; i += 512) cur[i] = cntG[i * NCHK + blockIdx.x];
    __syncthreads();
    int e0 = blockIdx.x * CHUNK;
    int e1 = min(e0 + CHUNK, N_EDGES);
    for (int e = e0 + tid; e < e1; e += 512) {
        int r = ei[e];
        int c = ei[N_EDGES + e];
        int wb = __float_as_int(ew[e]);
        int p = atomicAdd(&cur[c >> BIN_SHIFT], 1);
        binned[p] = make_int2(((c & 63) << 16) | r, wb);
        int q = atomicAdd(&cur[NBIN + (r >> BIN_SHIFT)], 1);
        binned[q] = make_int2(((r & 63) << 16) | c, wb);
    }
}

__device__ __forceinline__ void bin_range(const int* cntG, int b, int& lo, int& hi) {
    lo = cntG[b * NCHK];
    hi = (b + 1 < 2 * NBIN) ? cntG[(b + 1) * NCHK] : 2 * N_EDGES;
}

// 4. per-bin degrees + per-node counts (both dirs, one launch); linear stream.
__global__ __launch_bounds__(512) void bindeg_kernel(
    const int* __restrict__ cntG, const int2* __restrict__ binned,
    int* __restrict__ binCnt, float* __restrict__ ws_f) {
    __shared__ float wsum[64];
    __shared__ int cnt[64];
    int tid = threadIdx.x;
    int b = blockIdx.x;
    int dir = (b >= NBIN) ? 1 : 0;
    if (tid < 64) { wsum[tid] = 0.f; cnt[tid] = 0; }
    __syncthreads();
    int lo, hi;
    bin_range(cntG, b, lo, hi);
    for (int p = lo + tid; p < hi; p += 512) {
        int2 v = binned[p];
        int d = v.x >> 16;
        atomicAdd(&cnt[d], 1);
        atomicAdd(&wsum[d], __int_as_float(v.y));
    }
    __syncthreads();
    if (tid < 64) {
        binCnt[b * 64 + tid] = cnt[tid];
        int node = (b - dir * NBIN) * 64 + tid;
        if (node < N_NODES) {
            float s = wsum[tid];
            float* rdeg = ws_f + (dir == 0 ? WS_RDEG_IN : WS_RDEG_OUT);
            rdeg[node] = (s != 0.f) ? (1.f / s) : 0.f;
        }
    }
}

// 5. fused in-LDS binsort + register gather, one direction per launch.
__global__ __launch_bounds__(512) void fgather_kernel(
    const float4* __restrict__ x4, const int* __restrict__ cntG,
    const int* __restrict__ binCnt, const int2* __restrict__ binned,
    float* __restrict__ ws_f, int dir) {
    __shared__ int2 s_edge[FG_CAP];  // 20.5 KB
    __shared__ int s_off[65];
    __shared__ int s_cur[64];
    __shared__ int sc[64];
    int tid = threadIdx.x;
    int b = dir * NBIN + blockIdx.x;

    // A: exclusive scan of 64 counts
    int v = (tid < 64) ? binCnt[b * 64 + tid] : 0;
    if (tid < 64) sc[tid] = v;
    __syncthreads();
    for (int off = 1; off < 64; off <<= 1) {
        int u = (tid < 64 && tid >= off) ? sc[tid - off] : 0;
        __syncthreads();
        if (tid < 64) sc[tid] += u;
        __syncthreads();
    }
    if (tid < 64) {
        s_off[tid] = sc[tid] - v;
        s_cur[tid] = sc[tid] - v;
    }
    if (tid == 63) s_off[64] = sc[63];
    __syncthreads();

    // B: scatter into LDS sorted order (linear read of binned)
    int lo, hi;
    bin_range(cntG, b, lo, hi);
    int n_e = hi - lo;
    for (int p = tid; p < n_e; p += 512) {
        int2 ev = binned[lo + p];
        int rk = atomicAdd(&s_cur[ev.x >> 16], 1);
        if (rk < FG_CAP) s_edge[rk] = ev;
    }
    __syncthreads();

    // C: register-accumulating gather; coef = w * rdeg[src]
    const float* rdeg = ws_f + (dir == 0 ? WS_RDEG_OUT : WS_RDEG_IN);
    float4* outp = (float4*)(ws_f + (dir == 0 ? WS_TXO : WS_TXI));
    int lane = tid & 7;
    int nl = tid >> 3;
    int p = s_off[nl], end = s_off[nl + 1];
    float4 acc = make_float4(0.f, 0.f, 0.f, 0.f);
    for (; p + 1 < end; p += 2) {
        int2 v0 = s_edge[p], v1 = s_edge[p + 1];
        int s0 = v0.x & 0xffff, s1 = v1.x & 0xffff;
        float c0 = __int_as_float(v0.y) * rdeg[s0];
        float c1 = __int_as_float(v1.y) * rdeg[s1];
        float4 a = x4[s0 * 8 + lane];
        float4 bb = x4[s1 * 8 + lane];
        acc.x += c0 * a.x + c1 * bb.x;
        acc.y += c0 * a.y + c1 * bb.y;
        acc.z += c0 * a.z + c1 * bb.z;
        acc.w += c0 * a.w + c1 * bb.w;
    }
    if (p < end) {
        int2 v0 = s_edge[p];
        int s0 = v0.x & 0xffff;
        float c0 = __int_as_float(v0.y) * rdeg[s0];
        float4 a = x4[s0 * 8 + lane];
        acc.x += c0 * a.x;
        acc.y += c0 * a.y;
        acc.z += c0 * a.z;
        acc.w += c0 * a.w;
    }
    int node = blockIdx.x * 64 + nl;
    if (node < N_NODES) outp[node * 8 + lane] = acc;
}

// 6. Dense epilogue via bf16 MFMA (round-11 rewrite).
// Per block: C[64 nodes x 128 (z|h)] = A[64x96]_bf16 x B[96x128]_bf16 + bias,
// 4 waves x 8 N-tiles x 3 K-steps of v_mfma_f32_16x16x32_bf16.
// A in LDS, stride 104 bf16 (208 B = 13x16B: aligned b128 reads, bank-balanced).
// B copied linearly from wprep's pre-swizzled buffer.
// A-frag: A[m=lane&15][k=quad*8+j]; B-frag: B[k=quad*8+j][n=lane&15];
// C/D: col(n)=lane&15, row(m)=quad*4+reg  [m89/m91-verified mapping].
#define DN_GROUP 64
#define DN_BLOCKS ((N_NODES + DN_GROUP - 1) / DN_GROUP)  // 782
__global__ __launch_bounds__(256) void dense_kernel(
    const float4* __restrict__ x4,
    const float4* __restrict__ txo4, const float4* __restrict__ txi4,
    const unsigned short* __restrict__ wbf,
    const float* __restrict__ bz, const float* __restrict__ bh,
    const float* __restrict__ Wlin, const float* __restrict__ blin,
    float* __restrict__ out) {
    __shared__ unsigned short sA[64 * 104];  // 13.0 KB
    __shared__ unsigned short sB[12288];     // 24.0 KB (37.9 KB total -> 4 blk/CU)

    int tid = threadIdx.x;
    int lane = tid & 63, w = tid >> 6;
    int lm = lane & 15, quad = lane >> 4;

    // B: linear copy of pre-swizzled bf16 weights (12288 ushort = 3072 ushort4)
    for (int idx = tid; idx < 3072; idx += 256)
        *(ushort4*)&sB[idx * 4] = ((const ushort4*)wbf)[idx];

    // A: stage 64 nodes x 96 ch, fp32 -> bf16
    int node0 = blockIdx.x * DN_GROUP;
    for (int idx = tid; idx < 64 * 24; idx += 256) {
        int nl = idx / 24, q = idx - nl * 24;
        int node = node0 + nl;
        float4 v = make_float4(0.f, 0.f, 0.f, 0.f);
        if (node < N_NODES) {
            if (q < 8)       v = x4[node * 8 + q];
            else if (q < 16) v = txo4[node * 8 + (q - 8)];
            else             v = txi4[node * 8 + (q - 16)];
        }
        ushort4 bq;
        bq.x = f2bf(v.x); bq.y = f2bf(v.y); bq.z = f2bf(v.z); bq.w = f2bf(v.w);
        *(ushort4*)&sA[nl * 104 + q * 4] = bq;
    }

    // per-lane bias/Wlin for output cols o = lm + 16*bn, bn=0..3
    float bzv[4], bhv[4], wlv[4];
#pragma unroll
    for (int bn = 0; bn < 4; ++bn) {
        int o = lm + 16 * bn;
        bzv[bn] = bz[o]; bhv[bn] = bh[o]; wlv[bn] = Wlin[o];
    }
    float bl = blin[0];
    __syncthreads();

    f32x4 acc[8];
#pragma unroll
    for (int bn = 0; bn < 4; ++bn) {
        acc[bn]     = (f32x4){bzv[bn], bzv[bn], bzv[bn], bzv[bn]};
        acc[bn + 4] = (f32x4){bhv[bn], bhv[bn], bhv[bn], bhv[bn]};
    }
#pragma unroll
    for (int kk = 0; kk < 3; ++kk) {
        bf16x8 af = *(const bf16x8*)&sA[(w * 16 + lm) * 104 + kk * 32 + quad * 8];
#pragma unroll
        for (int bn = 0; bn < 8; ++bn) {
            bf16x8 bf = *(const bf16x8*)&sB[((kk * 8 + bn) * 64 + lane) * 8];
            acc[bn] = __builtin_amdgcn_mfma_f32_16x16x32_bf16(af, bf, acc[bn], 0, 0, 0);
        }
    }

    // epilogue: lane holds az=acc[bn][reg], ah=acc[bn+4][reg] for node
    // m = w*16 + quad*4 + reg, output o = lm + 16*bn
    float partial[4] = {0.f, 0.f, 0.f, 0.f};
#pragma unroll
    for (int bn = 0; bn < 4; ++bn) {
#pragma unroll
        for (int reg = 0; reg < 4; ++reg) {
            float az = acc[bn][reg], ah = acc[bn + 4][reg];
            float z = 1.f / (1.f + __expf(-az));
            float ht = 1.f - 2.f / (__expf(2.f * ah) + 1.f);
            partial[reg] += fmaxf((1.f - z) * ht, 0.f) * wlv[bn];
        }
    }
#pragma unroll
    for (int reg = 0; reg < 4; ++reg) {
        float s = partial[reg];
        s += __shfl_xor(s, 1, 64);
        s += __shfl_xor(s, 2, 64);
        s += __shfl_xor(s, 4, 64);
        s += __shfl_xor(s, 8, 64);
        if (lm == 0) {
            int node = node0 + w * 16 + quad * 4 + reg;
            if (node < N_NODES) out[node] = s + bl;
        }
    }
}

extern "C" void kernel_launch(void* const* d_in, const int* in_sizes, int n_in,
                              void* d_out, int out_size, void* d_ws, size_t ws_size,
                              hipStream_t stream) {
    const float* x = (const float*)d_in[0];
    const int* ei = (const int*)d_in[1];
    const float* ew = (const float*)d_in[2];
    const float* Wz = (const float*)d_in[3];
    const float* bz = (const float*)d_in[4];
    // d_in[5]=Wr, d_in[6]=br dead: H0==0 makes the reset gate a no-op
    const float* Wh = (const float*)d_in[7];
    const float* bh = (const float*)d_in[8];
    const float* Wlin = (const float*)d_in[9];
    const float* blin = (const float*)d_in[10];
    float* out = (float*)d_out;
    float* wf = (float*)d_ws;
    int* wi = (int*)d_ws;
    int2* binned = (int2*)(wi + WS_BINNED);

    // 0. weight prep (bf16, B-fragment order)
    wprep_kernel<<<48, 256, 0, stream>>>(Wz, Wh, (unsigned short*)(wi + WS_WBF));
    // 1. coarse per-chunk histograms, both dirs
    hist_kernel<<<NCHK, 512, 0, stream>>>(ei, wi + WS_CNTG);
    // 2. exclusive scan of the (dir,bin,chunk) count matrix
    scan_partial_kernel<<<SCAN_BLOCKS, 256, 0, stream>>>(
        (const int4*)(wi + WS_CNTG), wi + WS_BLKSUM, CNTG_N4);
    scan_blocksum_kernel<<<1, 256, 0, stream>>>(wi + WS_BLKSUM, SCAN_BLOCKS);
    scan_final_kernel<<<SCAN_BLOCKS, 256, 0, stream>>>(
        (int4*)(wi + WS_CNTG), wi + WS_BLKSUM, CNTG_N4);
    // 3. partition both dirs (payload int2 = {dstLocal<<16|src, w})
    partition_kernel<<<NCHK, 512, 0, stream>>>(ei, ew, wi + WS_CNTG, binned);
    // 4. per-bin degrees + saved node counts (both dirs, linear stream)
    bindeg_kernel<<<2 * NBIN, 512, 0, stream>>>(
        wi + WS_CNTG, binned, wi + WS_BINCNT, wf);
    // 5a. fused binsort+gather dir0 -> Tx_o
    fgather_kernel<<<NBIN, 512, 0, stream>>>(
        (const float4*)x, wi + WS_CNTG, wi + WS_BINCNT, binned, wf, 0);
    // 5b. fused binsort+gather dir1 -> Tx_i (writes over dead dir0 binned half)
    fgather_kernel<<<NBIN, 512, 0, stream>>>(
        (const float4*)x, wi + WS_CNTG, wi + WS_BINCNT, binned, wf, 1);
    // 6. MFMA dense epilogue
    dense_kernel<<<DN_BLOCKS, 256, 0, stream>>>(
        (const float4*)x, (const float4*)(wf + WS_TXO), (const float4*)(wf + WS_TXI),
        (const unsigned short*)(wi + WS_WBF), bz, bh, Wlin, blin, out);
}

// Round 12
// 215.488 us; speedup vs baseline: 1.7166x; 1.0953x over previous
//
#include <hip/hip_runtime.h>
#include <math.h>

#define N_NODES 50000
#define N_EDGES 1600000
#define IN_CH 32
#define HID 64

// ---------------- pipeline (10 dispatches, zero global atomics) ------------
// wprep -> hist -> scan(3) -> partition(coalesced, both dirs as 2*NCHK blocks)
//   -> bindeg -> fgather(dir0) -> fgather(dir1) -> dense(MFMA)
// Bins: 128 dst-nodes (bin = dst>>7), NBIN=391 per dir.
// Round-12 change: partition re-stages each chunk BIN-SORTED in LDS and
// writes out linearly -> consecutive threads hit consecutive global
// addresses (runs ~10.5 edges = 84 B >= 1 line) -> stores coalesce into
// near-full lines instead of 3.2M scattered 8 B transactions (R11: 82 MB
// writeback for 25.6 MB logical, ~57 G stores/s transaction wall).
// Payload int2 {(dstLocal<<16)|src, w_bits}; bin id rides bits 23..31 inside
// the partition kernel only (stripped on global write).
#define NBIN 391
#define BIN_SHIFT 7
#define CHUNK 4096
#define NCHK ((N_EDGES + CHUNK - 1) / CHUNK)   // 391
#define CNTG_N (2 * NBIN * NCHK)               // 305762
#define CNTG_N4 ((CNTG_N + 3) / 4)             // 76441 (2 pad ints at tail)
#define SCAN_BLOCKS ((CNTG_N4 + 1023) / 1024)  // 75
#define FG_CAP 4608   // bin capacity: mean 4096 + 8 sigma (Binomial)

// ---------------- workspace layout (int element offsets into d_ws)
#define WS_RDEG_OUT 0          // 50000 f (row-degree reciprocals, from dir1 bins)
#define WS_RDEG_IN  50000      // 50000 f (col-degree reciprocals, from dir0 bins)
#define WS_CNTG     100000     // 305764 i ((dir,bin,chunk) counts; scanned in place)
#define WS_BLKSUM   405764     // 128 i
#define WS_WBF      405892     // 6144 i = 12288 ushort (bf16 weights, B-frag order)
#define WS_BINCNT   412036     // 100096 i (782 bins x 128 per-node counts)
#define WS_BINNED   512132     // int2[3.2M] = 6400000 i (dir0 half then dir1 half)
#define WS_TXO      6912132    // 1600000 f
#define WS_TXI      512132     // 1600000 f -- ALIASES binned dir0 half (dead by then)
#define WS_END      8512132    // 34.0 MB high-water (< proven 40 MB)

typedef __attribute__((ext_vector_type(8))) short bf16x8;
typedef __attribute__((ext_vector_type(4))) float f32x4;

__device__ __forceinline__ unsigned short f2bf(float f) {  // RNE fp32 -> bf16
    unsigned int u = __float_as_uint(f);
    return (unsigned short)((u + 0x7fffu + ((u >> 16) & 1u)) >> 16);
}

// 0. weight prep: combine diffusion slabs, bf16-convert, store in the EXACT
// B-fragment order used by dense: idx = ((kk*8+bn)*64+lane)*8 + j holds
// Bmat[k=kk*32+(lane>>4)*8+j][n=bn*16+(lane&15)], Bmat = [Wz_eff | Wh_eff].
__global__ __launch_bounds__(256) void wprep_kernel(
    const float* __restrict__ Wz, const float* __restrict__ Wh,
    unsigned short* __restrict__ wbf) {
    int idx = blockIdx.x * 256 + threadIdx.x;
    if (idx >= 12288) return;
    int j = idx & 7, ln = (idx >> 3) & 63, bn = (idx >> 9) & 7, kk = idx >> 12;
    int k = kk * 32 + (ln >> 4) * 8 + j;
    int n = bn * 16 + (ln & 15);
    int slab = k >> 5, c = k & 31;
    const float* W = (n < 64) ? Wz : Wh;
    int o = n & 63;
    float v;
    if (slab == 0)      v = W[c * 64 + o] + W[(2 * 96 + c) * 64 + o];
    else if (slab == 1) v = W[(96 + c) * 64 + o];
    else                v = W[(3 * 96 + c) * 64 + o];
    wbf[idx] = f2bf(v);
}

// 1. per-chunk coarse histograms, both dirs (LDS atomics; fully writes cntG)
__global__ __launch_bounds__(512) void hist_kernel(const int* __restrict__ ei,
                                                   int* __restrict__ cntG) {
    __shared__ int h[2 * NBIN];
    int tid = threadIdx.x;
    for (int i = tid; i < 2 * NBIN; i += 512) h[i] = 0;
    __syncthreads();
    int e0 = blockIdx.x * CHUNK;
    int e1 = min(e0 + CHUNK, N_EDGES);
    for (int e = e0 + tid; e < e1; e += 512) {
        int r = ei[e];
        int c = ei[N_EDGES + e];
        atomicAdd(&h[c >> BIN_SHIFT], 1);           // dir0: group by col
        atomicAdd(&h[NBIN + (r >> BIN_SHIFT)], 1);  // dir1: group by row
    }
    __syncthreads();
    for (int i = tid; i < 2 * NBIN; i += 512) cntG[i * NCHK + blockIdx.x] = h[i];
}

// ---- 3-phase exclusive scan over cntG ----
__global__ __launch_bounds__(256) void scan_partial_kernel(
    const int4* __restrict__ cnt4, int* __restrict__ blksum, int n4) {
    __shared__ int s[256];
    int t = threadIdx.x;
    int base4 = blockIdx.x * 1024 + t * 4;
    int total = 0;
#pragma unroll
    for (int j = 0; j < 4; ++j) {
        int idx = base4 + j;
        if (idx < n4) {
            int4 v = cnt4[idx];
            total += v.x + v.y + v.z + v.w;
        }
    }
    s[t] = total;
    __syncthreads();
    for (int off = 128; off > 0; off >>= 1) {
        if (t < off) s[t] += s[t + off];
        __syncthreads();
    }
    if (t == 0) blksum[blockIdx.x] = s[0];
}

__global__ __launch_bounds__(256) void scan_blocksum_kernel(int* __restrict__ blksum, int nb) {
    __shared__ int s[256];
    int t = threadIdx.x;
    int v = (t < nb) ? blksum[t] : 0;
    s[t] = v;
    __syncthreads();
    for (int off = 1; off < 256; off <<= 1) {
        int u = (t >= off) ? s[t - off] : 0;
        __syncthreads();
        s[t] += u;
        __syncthreads();
    }
    if (t < nb) blksum[t] = s[t] - v;  // exclusive
}

__global__ __launch_bounds__(256) void scan_final_kernel(
    int4* __restrict__ cnt4, const int* __restrict__ blksum, int n4) {
    __shared__ int s[256];
    int t = threadIdx.x;
    int base4 = blockIdx.x * 1024 + t * 4;
    int4 vals[4];
    int total = 0;
#pragma unroll
    for (int j = 0; j < 4; ++j) {
        int idx = base4 + j;
        vals[j] = (idx < n4) ? cnt4[idx] : make_int4(0, 0, 0, 0);
        total += vals[j].x + vals[j].y + vals[j].z + vals[j].w;
    }
    s[t] = total;
    __syncthreads();
    for (int off = 1; off < 256; off <<= 1) {
        int u = (t >= off) ? s[t - off] : 0;
        __syncthreads();
        s[t] += u;
        __syncthreads();
    }
    int run = blksum[blockIdx.x] + s[t] - total;
#pragma unroll
    for (int j = 0; j < 4; ++j) {
        int idx = base4 + j;
        int4 v = vals[j];
        int4 o;
        o.x = run; run += v.x;
        o.y = run; run += v.y;
        o.z = run; run += v.z;
        o.w = run; run += v.w;
        if (idx < n4) cnt4[idx] = o;
    }
}

// 3. COALESCED partition. One block = one (dir, chunk). Pass 1: rank edges
// per bin with LDS atomics. Scan the 391-bin chunk histogram in-block.
// Stage the chunk bin-sorted in LDS. Pass 2: linear write-out -- consecutive
// threads write consecutive global addresses within each bin run.
__global__ __launch_bounds__(512) void partition_kernel(
    const int* __restrict__ ei, const float* __restrict__ ew,
    const int* __restrict__ cntG, int2* __restrict__ binned) {
    __shared__ int2 stg[CHUNK];      // 32 KB
    __shared__ int hist[NBIN];       // counts -> (after scan) local starts
    __shared__ int gStart[NBIN];
    __shared__ int sc[512];
    int tid = threadIdx.x;
    int dir = (blockIdx.x >= NCHK) ? 1 : 0;
    int chunk = blockIdx.x - dir * NCHK;

    for (int i = tid; i < NBIN; i += 512) hist[i] = 0;
    __syncthreads();

    int e0 = chunk * CHUNK;
    int n_e = min(CHUNK, N_EDGES - e0);
    int binv[8], rankv[8];
    int2 pay[8];
#pragma unroll
    for (int j = 0; j < 8; ++j) {
        int idx = tid + j * 512;
        if (idx < n_e) {
            int e = e0 + idx;
            int r = ei[e];
            int c = ei[N_EDGES + e];
            int dst = dir ? r : c;
            int src = dir ? c : r;
            int b = dst >> BIN_SHIFT;
            binv[j] = b;
            rankv[j] = atomicAdd(&hist[b], 1);
            pay[j] = make_int2((int)(((unsigned)b << 23) | ((unsigned)(dst & 127) << 16) |
                                     (unsigned)src),
                               __float_as_int(ew[e]));
        } else {
            binv[j] = -1;
        }
    }
    __syncthreads();
    // exclusive scan of hist[0..NBIN) -> local starts (in hist), load gStart
    int v = (tid < NBIN) ? hist[tid] : 0;
    sc[tid] = v;
    __syncthreads();
    for (int off = 1; off < 512; off <<= 1) {
        int u = (tid >= off) ? sc[tid - off] : 0;
        __syncthreads();
        sc[tid] += u;
        __syncthreads();
    }
    if (tid < NBIN) {
        hist[tid] = sc[tid] - v;  // local start
        gStart[tid] = cntG[(dir * NBIN + tid) * NCHK + chunk];
    }
    __syncthreads();
    // stage bin-sorted
#pragma unroll
    for (int j = 0; j < 8; ++j)
        if (binv[j] >= 0) stg[hist[binv[j]] + rankv[j]] = pay[j];
    __syncthreads();
    // linear write-out (coalesced within bin runs); strip bin bits
    for (int p = tid; p < n_e; p += 512) {
        int2 v2 = stg[p];
        int b = (int)(((unsigned)v2.x) >> 23);
        int gpos = gStart[b] + (p - hist[b]);
        binned[gpos] = make_int2(v2.x & 0x7FFFFF, v2.y);
    }
}

__device__ __forceinline__ void bin_range(const int* cntG, int b, int& lo, int& hi) {
    lo = cntG[b * NCHK];
    hi = (b + 1 < 2 * NBIN) ? cntG[(b + 1) * NCHK] : 2 * N_EDGES;
}

// 4. per-bin degrees + per-node counts (both dirs, one launch); linear stream.
__global__ __launch_bounds__(512) void bindeg_kernel(
    const int* __restrict__ cntG, const int2* __restrict__ binned,
    int* __restrict__ binCnt, float* __restrict__ ws_f) {
    __shared__ float wsum[128];
    __shared__ int cnt[128];
    int tid = threadIdx.x;
    int b = blockIdx.x;
    int dir = (b >= NBIN) ? 1 : 0;
    if (tid < 128) { wsum[tid] = 0.f; cnt[tid] = 0; }
    __syncthreads();
    int lo, hi;
    bin_range(cntG, b, lo, hi);
    for (int p = lo + tid; p < hi; p += 512) {
        int2 v = binned[p];
        int d = v.x >> 16;  // dstLocal (7 bits; bin bits stripped by partition)
        atomicAdd(&cnt[d], 1);
        atomicAdd(&wsum[d], __int_as_float(v.y));
    }
    __syncthreads();
    if (tid < 128) {
        binCnt[b * 128 + tid] = cnt[tid];
        int node = (b - dir * NBIN) * 128 + tid;
        if (node < N_NODES) {
            float s = wsum[tid];
            float* rdeg = ws_f + (dir == 0 ? WS_RDEG_IN : WS_RDEG_OUT);
            rdeg[node] = (s != 0.f) ? (1.f / s) : 0.f;
        }
    }
}

// 5. fused in-LDS binsort + register gather, one direction per launch.
__global__ __launch_bounds__(512) void fgather_kernel(
    const float4* __restrict__ x4, const int* __restrict__ cntG,
    const int* __restrict__ binCnt, const int2* __restrict__ binned,
    float* __restrict__ ws_f, int dir) {
    __shared__ int2 s_edge[FG_CAP];  // 36.9 KB
    __shared__ int s_off[129];
    __shared__ int s_cur[128];
    __shared__ int sc[128];
    int tid = threadIdx.x;
    int b = dir * NBIN + blockIdx.x;

    // A: exclusive scan of 128 counts
    int v = (tid < 128) ? binCnt[b * 128 + tid] : 0;
    if (tid < 128) sc[tid] = v;
    __syncthreads();
    for (int off = 1; off < 128; off <<= 1) {
        int u = (tid < 128 && tid >= off) ? sc[tid - off] : 0;
        __syncthreads();
        if (tid < 128) sc[tid] += u;
        __syncthreads();
    }
    if (tid < 128) {
        s_off[tid] = sc[tid] - v;
        s_cur[tid] = sc[tid] - v;
    }
    if (tid == 127) s_off[128] = sc[127];
    __syncthreads();

    // B: scatter into LDS sorted order (linear read of binned)
    int lo, hi;
    bin_range(cntG, b, lo, hi);
    int n_e = hi - lo;
    for (int p = tid; p < n_e; p += 512) {
        int2 ev = binned[lo + p];
        int rk = atomicAdd(&s_cur[ev.x >> 16], 1);
        if (rk < FG_CAP) s_edge[rk] = ev;
    }
    __syncthreads();

    // C: register-accumulating gather; coef = w * rdeg[src]
    const float* rdeg = ws_f + (dir == 0 ? WS_RDEG_OUT : WS_RDEG_IN);
    float4* outp = (float4*)(ws_f + (dir == 0 ? WS_TXO : WS_TXI));
    int lane = tid & 7;
#pragma unroll
    for (int it = 0; it < 2; ++it) {
        int nl = it * 64 + (tid >> 3);
        int p = s_off[nl], end = s_off[nl + 1];
        float4 acc = make_float4(0.f, 0.f, 0.f, 0.f);
        for (; p + 1 < end; p += 2) {
            int2 v0 = s_edge[p], v1 = s_edge[p + 1];
            int s0 = v0.x & 0xffff, s1 = v1.x & 0xffff;
            float c0 = __int_as_float(v0.y) * rdeg[s0];
            float c1 = __int_as_float(v1.y) * rdeg[s1];
            float4 a = x4[s0 * 8 + lane];
            float4 bb = x4[s1 * 8 + lane];
            acc.x += c0 * a.x + c1 * bb.x;
            acc.y += c0 * a.y + c1 * bb.y;
            acc.z += c0 * a.z + c1 * bb.z;
            acc.w += c0 * a.w + c1 * bb.w;
        }
        if (p < end) {
            int2 v0 = s_edge[p];
            int s0 = v0.x & 0xffff;
            float c0 = __int_as_float(v0.y) * rdeg[s0];
            float4 a = x4[s0 * 8 + lane];
            acc.x += c0 * a.x;
            acc.y += c0 * a.y;
            acc.z += c0 * a.z;
            acc.w += c0 * a.w;
        }
        int node = blockIdx.x * 128 + nl;
        if (node < N_NODES) outp[node * 8 + lane] = acc;
    }
}

// 6. Dense epilogue via bf16 MFMA (unchanged from round 11).
#define DN_GROUP 64
#define DN_BLOCKS ((N_NODES + DN_GROUP - 1) / DN_GROUP)  // 782
__global__ __launch_bounds__(256) void dense_kernel(
    const float4* __restrict__ x4,
    const float4* __restrict__ txo4, const float4* __restrict__ txi4,
    const unsigned short* __restrict__ wbf,
    const float* __restrict__ bz, const float* __restrict__ bh,
    const float* __restrict__ Wlin, const float* __restrict__ blin,
    float* __restrict__ out) {
    __shared__ unsigned short sA[64 * 104];  // 13.0 KB
    __shared__ unsigned short sB[12288];     // 24.0 KB

    int tid = threadIdx.x;
    int lane = tid & 63, w = tid >> 6;
    int lm = lane & 15, quad = lane >> 4;

    for (int idx = tid; idx < 3072; idx += 256)
        *(ushort4*)&sB[idx * 4] = ((const ushort4*)wbf)[idx];

    int node0 = blockIdx.x * DN_GROUP;
    for (int idx = tid; idx < 64 * 24; idx += 256) {
        int nl = idx / 24, q = idx - nl * 24;
        int node = node0 + nl;
        float4 v = make_float4(0.f, 0.f, 0.f, 0.f);
        if (node < N_NODES) {
            if (q < 8)       v = x4[node * 8 + q];
            else if (q < 16) v = txo4[node * 8 + (q - 8)];
            else             v = txi4[node * 8 + (q - 16)];
        }
        ushort4 bq;
        bq.x = f2bf(v.x); bq.y = f2bf(v.y); bq.z = f2bf(v.z); bq.w = f2bf(v.w);
        *(ushort4*)&sA[nl * 104 + q * 4] = bq;
    }

    float bzv[4], bhv[4], wlv[4];
#pragma unroll
    for (int bn = 0; bn < 4; ++bn) {
        int o = lm + 16 * bn;
        bzv[bn] = bz[o]; bhv[bn] = bh[o]; wlv[bn] = Wlin[o];
    }
    float bl = blin[0];
    __syncthreads();

    f32x4 acc[8];
#pragma unroll
    for (int bn = 0; bn < 4; ++bn) {
        acc[bn]     = (f32x4){bzv[bn], bzv[bn], bzv[bn], bzv[bn]};
        acc[bn + 4] = (f32x4){bhv[bn], bhv[bn], bhv[bn], bhv[bn]};
    }
#pragma unroll
    for (int kk = 0; kk < 3; ++kk) {
        bf16x8 af = *(const bf16x8*)&sA[(w * 16 + lm) * 104 + kk * 32 + quad * 8];
#pragma unroll
        for (int bn = 0; bn < 8; ++bn) {
            bf16x8 bf = *(const bf16x8*)&sB[((kk * 8 + bn) * 64 + lane) * 8];
            acc[bn] = __builtin_amdgcn_mfma_f32_16x16x32_bf16(af, bf, acc[bn], 0, 0, 0);
        }
    }

    float partial[4] = {0.f, 0.f, 0.f, 0.f};
#pragma unroll
    for (int bn = 0; bn < 4; ++bn) {
#pragma unroll
        for (int reg = 0; reg < 4; ++reg) {
            float az = acc[bn][reg], ah = acc[bn + 4][reg];
            float z = 1.f / (1.f + __expf(-az));
            float ht = 1.f - 2.f / (__expf(2.f * ah) + 1.f);
            partial[reg] += fmaxf((1.f - z) * ht, 0.f) * wlv[bn];
        }
    }
#pragma unroll
    for (int reg = 0; reg < 4; ++reg) {
        float s = partial[reg];
        s += __shfl_xor(s, 1, 64);
        s += __shfl_xor(s, 2, 64);
        s += __shfl_xor(s, 4, 64);
        s += __shfl_xor(s, 8, 64);
        if (lm == 0) {
            int node = node0 + w * 16 + quad * 4 + reg;
            if (node < N_NODES) out[node] = s + bl;
        }
    }
}

extern "C" void kernel_launch(void* const* d_in, const int* in_sizes, int n_in,
                              void* d_out, int out_size, void* d_ws, size_t ws_size,
                              hipStream_t stream) {
    const float* x = (const float*)d_in[0];
    const int* ei = (const int*)d_in[1];
    const float* ew = (const float*)d_in[2];
    const float* Wz = (const float*)d_in[3];
    const float* bz = (const float*)d_in[4];
    // d_in[5]=Wr, d_in[6]=br dead: H0==0 makes the reset gate a no-op
    const float* Wh = (const float*)d_in[7];
    const float* bh = (const float*)d_in[8];
    const float* Wlin = (const float*)d_in[9];
    const float* blin = (const float*)d_in[10];
    float* out = (float*)d_out;
    float* wf = (float*)d_ws;
    int* wi = (int*)d_ws;
    int2* binned = (int2*)(wi + WS_BINNED);

    // 0. weight prep (bf16, B-fragment order)
    wprep_kernel<<<48, 256, 0, stream>>>(Wz, Wh, (unsigned short*)(wi + WS_WBF));
    // 1. coarse per-chunk histograms, both dirs
    hist_kernel<<<NCHK, 512, 0, stream>>>(ei, wi + WS_CNTG);
    // 2. exclusive scan of the (dir,bin,chunk) count matrix
    scan_partial_kernel<<<SCAN_BLOCKS, 256, 0, stream>>>(
        (const int4*)(wi + WS_CNTG), wi + WS_BLKSUM, CNTG_N4);
    scan_blocksum_kernel<<<1, 256, 0, stream>>>(wi + WS_BLKSUM, SCAN_BLOCKS);
    scan_final_kernel<<<SCAN_BLOCKS, 256, 0, stream>>>(
        (int4*)(wi + WS_CNTG), wi + WS_BLKSUM, CNTG_N4);
    // 3. coalesced partition (one block per dir x chunk; LDS re-staging)
    partition_kernel<<<2 * NCHK, 512, 0, stream>>>(ei, ew, wi + WS_CNTG, binned);
    // 4. per-bin degrees + saved node counts (both dirs, linear stream)
    bindeg_kernel<<<2 * NBIN, 512, 0, stream>>>(
        wi + WS_CNTG, binned, wi + WS_BINCNT, wf);
    // 5a. fused binsort+gather dir0 -> Tx_o
    fgather_kernel<<<NBIN, 512, 0, stream>>>(
        (const float4*)x, wi + WS_CNTG, wi + WS_BINCNT, binned, wf, 0);
    // 5b. fused binsort+gather dir1 -> Tx_i (writes over dead dir0 binned half)
    fgather_kernel<<<NBIN, 512, 0, stream>>>(
        (const float4*)x, wi + WS_CNTG, wi + WS_BINCNT, binned, wf, 1);
    // 6. MFMA dense epilogue
    dense_kernel<<<DN_BLOCKS, 256, 0, stream>>>(
        (const float4*)x, (const float4*)(wf + WS_TXO), (const float4*)(wf + WS_TXI),
        (const unsigned short*)(wi + WS_WBF), bz, bh, Wlin, blin, out);
}

// Round 13
// 206.753 us; speedup vs baseline: 1.7891x; 1.0422x over previous
//
#include <hip/hip_runtime.h>
#include <math.h>

#define N_NODES 50000
#define N_EDGES 1600000
#define IN_CH 32
#define HID 64

// ---------------- pipeline (10 dispatches, zero global atomics) ------------
// wprep -> hist -> scan(3) -> partition -> bindeg -> xconv -> fgather(both
// dirs, one launch) -> dense(MFMA)
// Bins: 128 dst-nodes (bin = dst>>7), NBIN=391 per dir.
// Round-13 changes: (a) xconv pre-scales x by rdeg into TWO bf16 copies
// (xs0 = x*rdeg_out for dir0, xs1 = x*rdeg_in for dir1; 3.2 MB each, fits
// per-XCD L2) -- fgather's per-edge work loses the rdeg fetch and halves its
// x bytes (64 B rows); (b) Tx stored as bf16 (dense rounds Tx to bf16 anyway
// -- the rounding just moves earlier, no new error at the dense input);
// (c) both fgather dirs merged into one 782-block launch.
// Real ws budget is 256 MiB (fillBufferAligned WRITE_SIZE), not 40 MB.
#define NBIN 391
#define BIN_SHIFT 7
#define CHUNK 4096
#define NCHK ((N_EDGES + CHUNK - 1) / CHUNK)   // 391
#define CNTG_N (2 * NBIN * NCHK)               // 305762
#define CNTG_N4 ((CNTG_N + 3) / 4)             // 76441 (2 pad ints at tail)
#define SCAN_BLOCKS ((CNTG_N4 + 1023) / 1024)  // 75
#define FG_CAP 4608   // bin capacity: mean 4096 + 8 sigma (Binomial)

// ---------------- workspace layout (int element offsets into d_ws)
#define WS_RDEG_OUT 0          // 50000 f (row-degree reciprocals, from dir1 bins)
#define WS_RDEG_IN  50000      // 50000 f (col-degree reciprocals, from dir0 bins)
#define WS_CNTG     100000     // 305764 i ((dir,bin,chunk) counts; scanned in place)
#define WS_BLKSUM   405764     // 128 i
#define WS_WBF      405892     // 6144 i = 12288 ushort (bf16 weights, B-frag order)
#define WS_BINCNT   412036     // 100096 i (782 bins x 128 per-node counts)
#define WS_XS0      512132     // 800000 i = 1.6M ushort (bf16 x*rdeg_out)
#define WS_XS1      1312132    // 800000 i (bf16 x*rdeg_in)
#define WS_TXO      2112132    // 800000 i (bf16 Tx_o, 50000 x 32)
#define WS_TXI      2912132    // 800000 i (bf16 Tx_i)
#define WS_BINNED   3712132    // int2[3.2M] = 6400000 i
#define WS_END      10112132   // 40.4 MB (ws is 256 MiB)

typedef __attribute__((ext_vector_type(8))) short bf16x8;
typedef __attribute__((ext_vector_type(4))) float f32x4;

__device__ __forceinline__ unsigned short f2bf(float f) {  // RNE fp32 -> bf16
    unsigned int u = __float_as_uint(f);
    return (unsigned short)((u + 0x7fffu + ((u >> 16) & 1u)) >> 16);
}
__device__ __forceinline__ float bf2f(unsigned short b) {
    return __uint_as_float((unsigned int)b << 16);
}

// 0. weight prep: combine diffusion slabs, bf16-convert, store in the EXACT
// B-fragment order used by dense: idx = ((kk*8+bn)*64+lane)*8 + j holds
// Bmat[k=kk*32+(lane>>4)*8+j][n=bn*16+(lane&15)], Bmat = [Wz_eff | Wh_eff].
__global__ __launch_bounds__(256) void wprep_kernel(
    const float* __restrict__ Wz, const float* __restrict__ Wh,
    unsigned short* __restrict__ wbf) {
    int idx = blockIdx.x * 256 + threadIdx.x;
    if (idx >= 12288) return;
    int j = idx & 7, ln = (idx >> 3) & 63, bn = (idx >> 9) & 7, kk = idx >> 12;
    int k = kk * 32 + (ln >> 4) * 8 + j;
    int n = bn * 16 + (ln & 15);
    int slab = k >> 5, c = k & 31;
    const float* W = (n < 64) ? Wz : Wh;
    int o = n & 63;
    float v;
    if (slab == 0)      v = W[c * 64 + o] + W[(2 * 96 + c) * 64 + o];
    else if (slab == 1) v = W[(96 + c) * 64 + o];
    else                v = W[(3 * 96 + c) * 64 + o];
    wbf[idx] = f2bf(v);
}

// 1. per-chunk coarse histograms, both dirs (LDS atomics; fully writes cntG)
__global__ __launch_bounds__(512) void hist_kernel(const int* __restrict__ ei,
                                                   int* __restrict__ cntG) {
    __shared__ int h[2 * NBIN];
    int tid = threadIdx.x;
    for (int i = tid; i < 2 * NBIN; i += 512) h[i] = 0;
    __syncthreads();
    int e0 = blockIdx.x * CHUNK;
    int e1 = min(e0 + CHUNK, N_EDGES);
    for (int e = e0 + tid; e < e1; e += 512) {
        int r = ei[e];
        int c = ei[N_EDGES + e];
        atomicAdd(&h[c >> BIN_SHIFT], 1);           // dir0: group by col
        atomicAdd(&h[NBIN + (r >> BIN_SHIFT)], 1);  // dir1: group by row
    }
    __syncthreads();
    for (int i = tid; i < 2 * NBIN; i += 512) cntG[i * NCHK + blockIdx.x] = h[i];
}

// ---- 3-phase exclusive scan over cntG ----
__global__ __launch_bounds__(256) void scan_partial_kernel(
    const int4* __restrict__ cnt4, int* __restrict__ blksum, int n4) {
    __shared__ int s[256];
    int t = threadIdx.x;
    int base4 = blockIdx.x * 1024 + t * 4;
    int total = 0;
#pragma unroll
    for (int j = 0; j < 4; ++j) {
        int idx = base4 + j;
        if (idx < n4) {
            int4 v = cnt4[idx];
            total += v.x + v.y + v.z + v.w;
        }
    }
    s[t] = total;
    __syncthreads();
    for (int off = 128; off > 0; off >>= 1) {
        if (t < off) s[t] += s[t + off];
        __syncthreads();
    }
    if (t == 0) blksum[blockIdx.x] = s[0];
}

__global__ __launch_bounds__(256) void scan_blocksum_kernel(int* __restrict__ blksum, int nb) {
    __shared__ int s[256];
    int t = threadIdx.x;
    int v = (t < nb) ? blksum[t] : 0;
    s[t] = v;
    __syncthreads();
    for (int off = 1; off < 256; off <<= 1) {
        int u = (t >= off) ? s[t - off] : 0;
        __syncthreads();
        s[t] += u;
        __syncthreads();
    }
    if (t < nb) blksum[t] = s[t] - v;  // exclusive
}

__global__ __launch_bounds__(256) void scan_final_kernel(
    int4* __restrict__ cnt4, const int* __restrict__ blksum, int n4) {
    __shared__ int s[256];
    int t = threadIdx.x;
    int base4 = blockIdx.x * 1024 + t * 4;
    int4 vals[4];
    int total = 0;
#pragma unroll
    for (int j = 0; j < 4; ++j) {
        int idx = base4 + j;
        vals[j] = (idx < n4) ? cnt4[idx] : make_int4(0, 0, 0, 0);
        total += vals[j].x + vals[j].y + vals[j].z + vals[j].w;
    }
    s[t] = total;
    __syncthreads();
    for (int off = 1; off < 256; off <<= 1) {
        int u = (t >= off) ? s[t - off] : 0;
        __syncthreads();
        s[t] += u;
        __syncthreads();
    }
    int run = blksum[blockIdx.x] + s[t] - total;
#pragma unroll
    for (int j = 0; j < 4; ++j) {
        int idx = base4 + j;
        int4 v = vals[j];
        int4 o;
        o.x = run; run += v.x;
        o.y = run; run += v.y;
        o.z = run; run += v.z;
        o.w = run; run += v.w;
        if (idx < n4) cnt4[idx] = o;
    }
}

// 3. COALESCED partition (round-12 design, unchanged). One block = one
// (dir, chunk); LDS re-staging makes the global write-out coalesced.
__global__ __launch_bounds__(512) void partition_kernel(
    const int* __restrict__ ei, const float* __restrict__ ew,
    const int* __restrict__ cntG, int2* __restrict__ binned) {
    __shared__ int2 stg[CHUNK];      // 32 KB
    __shared__ int hist[NBIN];       // counts -> (after scan) local starts
    __shared__ int gStart[NBIN];
    __shared__ int sc[512];
    int tid = threadIdx.x;
    int dir = (blockIdx.x >= NCHK) ? 1 : 0;
    int chunk = blockIdx.x - dir * NCHK;

    for (int i = tid; i < NBIN; i += 512) hist[i] = 0;
    __syncthreads();

    int e0 = chunk * CHUNK;
    int n_e = min(CHUNK, N_EDGES - e0);
    int binv[8], rankv[8];
    int2 pay[8];
#pragma unroll
    for (int j = 0; j < 8; ++j) {
        int idx = tid + j * 512;
        if (idx < n_e) {
            int e = e0 + idx;
            int r = ei[e];
            int c = ei[N_EDGES + e];
            int dst = dir ? r : c;
            int src = dir ? c : r;
            int b = dst >> BIN_SHIFT;
            binv[j] = b;
            rankv[j] = atomicAdd(&hist[b], 1);
            pay[j] = make_int2((int)(((unsigned)b << 23) | ((unsigned)(dst & 127) << 16) |
                                     (unsigned)src),
                               __float_as_int(ew[e]));
        } else {
            binv[j] = -1;
        }
    }
    __syncthreads();
    int v = (tid < NBIN) ? hist[tid] : 0;
    sc[tid] = v;
    __syncthreads();
    for (int off = 1; off < 512; off <<= 1) {
        int u = (tid >= off) ? sc[tid - off] : 0;
        __syncthreads();
        sc[tid] += u;
        __syncthreads();
    }
    if (tid < NBIN) {
        hist[tid] = sc[tid] - v;  // local start
        gStart[tid] = cntG[(dir * NBIN + tid) * NCHK + chunk];
    }
    __syncthreads();
#pragma unroll
    for (int j = 0; j < 8; ++j)
        if (binv[j] >= 0) stg[hist[binv[j]] + rankv[j]] = pay[j];
    __syncthreads();
    for (int p = tid; p < n_e; p += 512) {
        int2 v2 = stg[p];
        int b = (int)(((unsigned)v2.x) >> 23);
        int gpos = gStart[b] + (p - hist[b]);
        binned[gpos] = make_int2(v2.x & 0x7FFFFF, v2.y);
    }
}

__device__ __forceinline__ void bin_range(const int* cntG, int b, int& lo, int& hi) {
    lo = cntG[b * NCHK];
    hi = (b + 1 < 2 * NBIN) ? cntG[(b + 1) * NCHK] : 2 * N_EDGES;
}

// 4. per-bin degrees + per-node counts (both dirs, one launch); linear stream.
__global__ __launch_bounds__(512) void bindeg_kernel(
    const int* __restrict__ cntG, const int2* __restrict__ binned,
    int* __restrict__ binCnt, float* __restrict__ ws_f) {
    __shared__ float wsum[128];
    __shared__ int cnt[128];
    int tid = threadIdx.x;
    int b = blockIdx.x;
    int dir = (b >= NBIN) ? 1 : 0;
    if (tid < 128) { wsum[tid] = 0.f; cnt[tid] = 0; }
    __syncthreads();
    int lo, hi;
    bin_range(cntG, b, lo, hi);
    for (int p = lo + tid; p < hi; p += 512) {
        int2 v = binned[p];
        int d = v.x >> 16;
        atomicAdd(&cnt[d], 1);
        atomicAdd(&wsum[d], __int_as_float(v.y));
    }
    __syncthreads();
    if (tid < 128) {
        binCnt[b * 128 + tid] = cnt[tid];
        int node = (b - dir * NBIN) * 128 + tid;
        if (node < N_NODES) {
            float s = wsum[tid];
            float* rdeg = ws_f + (dir == 0 ? WS_RDEG_IN : WS_RDEG_OUT);
            rdeg[node] = (s != 0.f) ? (1.f / s) : 0.f;
        }
    }
}

// 4b. x pre-scale: xs0 = bf16(x * rdeg_out), xs1 = bf16(x * rdeg_in).
// One thread per (node, lane-of-8): float4 read x2 scales -> 2 ushort4 stores.
__global__ __launch_bounds__(256) void xconv_kernel(
    const float4* __restrict__ x4, const float* __restrict__ rdeg_out,
    const float* __restrict__ rdeg_in, ushort4* __restrict__ xs0,
    ushort4* __restrict__ xs1) {
    int i = blockIdx.x * 256 + threadIdx.x;
    if (i >= N_NODES * 8) return;
    int node = i >> 3;
    float4 v = x4[i];
    float a = rdeg_out[node], bsc = rdeg_in[node];
    ushort4 o0, o1;
    o0.x = f2bf(v.x * a); o0.y = f2bf(v.y * a);
    o0.z = f2bf(v.z * a); o0.w = f2bf(v.w * a);
    o1.x = f2bf(v.x * bsc); o1.y = f2bf(v.y * bsc);
    o1.z = f2bf(v.z * bsc); o1.w = f2bf(v.w * bsc);
    xs0[i] = o0;
    xs1[i] = o1;
}

// 5. fused in-LDS binsort + register gather, BOTH dirs in one launch.
// coef = w only (x rows pre-scaled by rdeg); x rows are bf16 (64 B).
__global__ __launch_bounds__(512) void fgather_kernel(
    const ushort4* __restrict__ xs0, const ushort4* __restrict__ xs1,
    const int* __restrict__ cntG, const int* __restrict__ binCnt,
    const int2* __restrict__ binned, float* __restrict__ ws_f) {
    __shared__ int2 s_edge[FG_CAP];  // 36.9 KB
    __shared__ int s_off[129];
    __shared__ int s_cur[128];
    __shared__ int sc[128];
    int tid = threadIdx.x;
    int b = blockIdx.x;
    int dir = (b >= NBIN) ? 1 : 0;
    int bin = b - dir * NBIN;

    // A: exclusive scan of 128 counts
    int v = (tid < 128) ? binCnt[b * 128 + tid] : 0;
    if (tid < 128) sc[tid] = v;
    __syncthreads();
    for (int off = 1; off < 128; off <<= 1) {
        int u = (tid < 128 && tid >= off) ? sc[tid - off] : 0;
        __syncthreads();
        if (tid < 128) sc[tid] += u;
        __syncthreads();
    }
    if (tid < 128) {
        s_off[tid] = sc[tid] - v;
        s_cur[tid] = sc[tid] - v;
    }
    if (tid == 127) s_off[128] = sc[127];
    __syncthreads();

    // B: scatter into LDS sorted order (linear read of binned)
    int lo, hi;
    bin_range(cntG, b, lo, hi);
    int n_e = hi - lo;
    for (int p = tid; p < n_e; p += 512) {
        int2 ev = binned[lo + p];
        int rk = atomicAdd(&s_cur[ev.x >> 16], 1);
        if (rk < FG_CAP) s_edge[rk] = ev;
    }
    __syncthreads();

    // C: register-accumulating gather; acc += w * xs[src]
    const ushort4* xs = (dir == 0) ? xs0 : xs1;
    ushort4* outp = (ushort4*)(ws_f + (dir == 0 ? WS_TXO : WS_TXI));
    int lane = tid & 7;
#pragma unroll
    for (int it = 0; it < 2; ++it) {
        int nl = it * 64 + (tid >> 3);
        int p = s_off[nl], end = s_off[nl + 1];
        float4 acc = make_float4(0.f, 0.f, 0.f, 0.f);
        for (; p + 1 < end; p += 2) {
            int2 v0 = s_edge[p], v1 = s_edge[p + 1];
            int s0 = v0.x & 0xffff, s1 = v1.x & 0xffff;
            float c0 = __int_as_float(v0.y);
            float c1 = __int_as_float(v1.y);
            ushort4 a = xs[s0 * 8 + lane];
            ushort4 bb = xs[s1 * 8 + lane];
            acc.x += c0 * bf2f(a.x) + c1 * bf2f(bb.x);
            acc.y += c0 * bf2f(a.y) + c1 * bf2f(bb.y);
            acc.z += c0 * bf2f(a.z) + c1 * bf2f(bb.z);
            acc.w += c0 * bf2f(a.w) + c1 * bf2f(bb.w);
        }
        if (p < end) {
            int2 v0 = s_edge[p];
            int s0 = v0.x & 0xffff;
            float c0 = __int_as_float(v0.y);
            ushort4 a = xs[s0 * 8 + lane];
            acc.x += c0 * bf2f(a.x);
            acc.y += c0 * bf2f(a.y);
            acc.z += c0 * bf2f(a.z);
            acc.w += c0 * bf2f(a.w);
        }
        int node = bin * 128 + nl;
        if (node < N_NODES) {
            ushort4 o;
            o.x = f2bf(acc.x); o.y = f2bf(acc.y);
            o.z = f2bf(acc.z); o.w = f2bf(acc.w);
            outp[node * 8 + lane] = o;
        }
    }
}

// 6. Dense epilogue via bf16 MFMA. Tx now arrives as bf16 -> raw int4 copies
// into LDS (no conversion); x part still fp32 -> bf16.
#define DN_GROUP 64
#define DN_BLOCKS ((N_NODES + DN_GROUP - 1) / DN_GROUP)  // 782
__global__ __launch_bounds__(256) void dense_kernel(
    const float4* __restrict__ x4,
    const int4* __restrict__ txo_b, const int4* __restrict__ txi_b,
    const unsigned short* __restrict__ wbf,
    const float* __restrict__ bz, const float* __restrict__ bh,
    const float* __restrict__ Wlin, const float* __restrict__ blin,
    float* __restrict__ out) {
    __shared__ unsigned short sA[64 * 104];  // 13.0 KB
    __shared__ unsigned short sB[12288];     // 24.0 KB

    int tid = threadIdx.x;
    int lane = tid & 63, w = tid >> 6;
    int lm = lane & 15, quad = lane >> 4;

    for (int idx = tid; idx < 3072; idx += 256)
        *(ushort4*)&sB[idx * 4] = ((const ushort4*)wbf)[idx];

    int node0 = blockIdx.x * DN_GROUP;
    // x part: 64 nodes x 8 float4 -> bf16
    for (int idx = tid; idx < 64 * 8; idx += 256) {
        int nl = idx >> 3, q = idx & 7;
        int node = node0 + nl;
        float4 v = (node < N_NODES) ? x4[node * 8 + q]
                                    : make_float4(0.f, 0.f, 0.f, 0.f);
        ushort4 bq;
        bq.x = f2bf(v.x); bq.y = f2bf(v.y); bq.z = f2bf(v.z); bq.w = f2bf(v.w);
        *(ushort4*)&sA[nl * 104 + q * 4] = bq;
    }
    // Tx part: 64 nodes x (4+4) int4 raw bf16 (8 ch per 16 B)
    for (int idx = tid; idx < 64 * 8; idx += 256) {
        int nl = idx >> 3, q = idx & 7;
        int node = node0 + nl;
        int4 v = make_int4(0, 0, 0, 0);
        if (node < N_NODES)
            v = (q < 4) ? txo_b[node * 4 + q] : txi_b[node * 4 + (q - 4)];
        *(int4*)&sA[nl * 104 + 32 + q * 8] = v;
    }

    float bzv[4], bhv[4], wlv[4];
#pragma unroll
    for (int bn = 0; bn < 4; ++bn) {
        int o = lm + 16 * bn;
        bzv[bn] = bz[o]; bhv[bn] = bh[o]; wlv[bn] = Wlin[o];
    }
    float bl = blin[0];
    __syncthreads();

    f32x4 acc[8];
#pragma unroll
    for (int bn = 0; bn < 4; ++bn) {
        acc[bn]     = (f32x4){bzv[bn], bzv[bn], bzv[bn], bzv[bn]};
        acc[bn + 4] = (f32x4){bhv[bn], bhv[bn], bhv[bn], bhv[bn]};
    }
#pragma unroll
    for (int kk = 0; kk < 3; ++kk) {
        bf16x8 af = *(const bf16x8*)&sA[(w * 16 + lm) * 104 + kk * 32 + quad * 8];
#pragma unroll
        for (int bn = 0; bn < 8; ++bn) {
            bf16x8 bf = *(const bf16x8*)&sB[((kk * 8 + bn) * 64 + lane) * 8];
            acc[bn] = __builtin_amdgcn_mfma_f32_16x16x32_bf16(af, bf, acc[bn], 0, 0, 0);
        }
    }

    float partial[4] = {0.f, 0.f, 0.f, 0.f};
#pragma unroll
    for (int bn = 0; bn < 4; ++bn) {
#pragma unroll
        for (int reg = 0; reg < 4; ++reg) {
            float az = acc[bn][reg], ah = acc[bn + 4][reg];
            float z = 1.f / (1.f + __expf(-az));
            float ht = 1.f - 2.f / (__expf(2.f * ah) + 1.f);
            partial[reg] += fmaxf((1.f - z) * ht, 0.f) * wlv[bn];
        }
    }
#pragma unroll
    for (int reg = 0; reg < 4; ++reg) {
        float s = partial[reg];
        s += __shfl_xor(s, 1, 64);
        s += __shfl_xor(s, 2, 64);
        s += __shfl_xor(s, 4, 64);
        s += __shfl_xor(s, 8, 64);
        if (lm == 0) {
            int node = node0 + w * 16 + quad * 4 + reg;
            if (node < N_NODES) out[node] = s + bl;
        }
    }
}

extern "C" void kernel_launch(void* const* d_in, const int* in_sizes, int n_in,
                              void* d_out, int out_size, void* d_ws, size_t ws_size,
                              hipStream_t stream) {
    const float* x = (const float*)d_in[0];
    const int* ei = (const int*)d_in[1];
    const float* ew = (const float*)d_in[2];
    const float* Wz = (const float*)d_in[3];
    const float* bz = (const float*)d_in[4];
    // d_in[5]=Wr, d_in[6]=br dead: H0==0 makes the reset gate a no-op
    const float* Wh = (const float*)d_in[7];
    const float* bh = (const float*)d_in[8];
    const float* Wlin = (const float*)d_in[9];
    const float* blin = (const float*)d_in[10];
    float* out = (float*)d_out;
    float* wf = (float*)d_ws;
    int* wi = (int*)d_ws;
    int2* binned = (int2*)(wi + WS_BINNED);

    // 0. weight prep (bf16, B-fragment order)
    wprep_kernel<<<48, 256, 0, stream>>>(Wz, Wh, (unsigned short*)(wi + WS_WBF));
    // 1. coarse per-chunk histograms, both dirs
    hist_kernel<<<NCHK, 512, 0, stream>>>(ei, wi + WS_CNTG);
    // 2. exclusive scan of the (dir,bin,chunk) count matrix
    scan_partial_kernel<<<SCAN_BLOCKS, 256, 0, stream>>>(
        (const int4*)(wi + WS_CNTG), wi + WS_BLKSUM, CNTG_N4);
    scan_blocksum_kernel<<<1, 256, 0, stream>>>(wi + WS_BLKSUM, SCAN_BLOCKS);
    scan_final_kernel<<<SCAN_BLOCKS, 256, 0, stream>>>(
        (int4*)(wi + WS_CNTG), wi + WS_BLKSUM, CNTG_N4);
    // 3. coalesced partition (one block per dir x chunk; LDS re-staging)
    partition_kernel<<<2 * NCHK, 512, 0, stream>>>(ei, ew, wi + WS_CNTG, binned);
    // 4. per-bin degrees + saved node counts (both dirs, linear stream)
    bindeg_kernel<<<2 * NBIN, 512, 0, stream>>>(
        wi + WS_CNTG, binned, wi + WS_BINCNT, wf);
    // 4b. pre-scaled bf16 x copies (xs0 = x*rdeg_out, xs1 = x*rdeg_in)
    xconv_kernel<<<(N_NODES * 8 + 255) / 256, 256, 0, stream>>>(
        (const float4*)x, wf + WS_RDEG_OUT, wf + WS_RDEG_IN,
        (ushort4*)(wi + WS_XS0), (ushort4*)(wi + WS_XS1));
    // 5. fused binsort+gather, both dirs -> bf16 Tx_o / Tx_i
    fgather_kernel<<<2 * NBIN, 512, 0, stream>>>(
        (const ushort4*)(wi + WS_XS0), (const ushort4*)(wi + WS_XS1),
        wi + WS_CNTG, wi + WS_BINCNT, binned, wf);
    // 6. MFMA dense epilogue (bf16 Tx inputs)
    dense_kernel<<<DN_BLOCKS, 256, 0, stream>>>(
        (const float4*)x, (const int4*)(wi + WS_TXO), (const int4*)(wi + WS_TXI),
        (const unsigned short*)(wi + WS_WBF), bz, bh, Wlin, blin, out);
}

// Round 14
// 198.063 us; speedup vs baseline: 1.8676x; 1.0439x over previous
//
#include <hip/hip_runtime.h>
#include <math.h>

#define N_NODES 50000
#define N_EDGES 1600000
#define IN_CH 32
#define HID 64

// ---------------- pipeline (10 dispatches, zero global atomics) ------------
// wprep -> hist -> scan(3) -> partition -> bindeg -> xconv -> fgather(both
// dirs, one launch) -> dense(MFMA)
// Bins: 128 dst-nodes (bin = dst>>7), NBIN=391 per dir.
// Round-14 change: ONE unscaled bf16 x copy (3.2 MB) + rdeg multiply inside
// fgather (random 4 B reads into 200 KB L2-resident tables). Round 13's two
// pre-scaled copies (6.4 MB) exceeded the 4 MB per-XCD L2 (each XCD sees
// bins of BOTH dirs) and thrashed: FETCH 125 MB vs ~32 MB logical. Single
// copy + tiny tables fit -> xs misses become L2 hits.
#define NBIN 391
#define BIN_SHIFT 7
#define CHUNK 4096
#define NCHK ((N_EDGES + CHUNK - 1) / CHUNK)   // 391
#define CNTG_N (2 * NBIN * NCHK)               // 305762
#define CNTG_N4 ((CNTG_N + 3) / 4)             // 76441 (2 pad ints at tail)
#define SCAN_BLOCKS ((CNTG_N4 + 1023) / 1024)  // 75
#define FG_CAP 4608   // bin capacity: mean 4096 + 8 sigma (Binomial)

// ---------------- workspace layout (int element offsets into d_ws)
#define WS_RDEG_OUT 0          // 50000 f (row-degree reciprocals, from dir1 bins)
#define WS_RDEG_IN  50000      // 50000 f (col-degree reciprocals, from dir0 bins)
#define WS_CNTG     100000     // 305764 i ((dir,bin,chunk) counts; scanned in place)
#define WS_BLKSUM   405764     // 128 i
#define WS_WBF      405892     // 6144 i = 12288 ushort (bf16 weights, B-frag order)
#define WS_BINCNT   412036     // 100096 i (782 bins x 128 per-node counts)
#define WS_XSB      512132     // 800000 i = 1.6M ushort (bf16 x, unscaled)
#define WS_TXO      1312132    // 800000 i (bf16 Tx_o, 50000 x 32)
#define WS_TXI      2112132    // 800000 i (bf16 Tx_i)
#define WS_BINNED   2912132    // int2[3.2M] = 6400000 i
#define WS_END      9312132    // 37.2 MB (ws is 256 MiB)

typedef __attribute__((ext_vector_type(8))) short bf16x8;
typedef __attribute__((ext_vector_type(4))) float f32x4;

__device__ __forceinline__ unsigned short f2bf(float f) {  // RNE fp32 -> bf16
    unsigned int u = __float_as_uint(f);
    return (unsigned short)((u + 0x7fffu + ((u >> 16) & 1u)) >> 16);
}
__device__ __forceinline__ float bf2f(unsigned short b) {
    return __uint_as_float((unsigned int)b << 16);
}

// 0. weight prep: combine diffusion slabs, bf16-convert, store in the EXACT
// B-fragment order used by dense: idx = ((kk*8+bn)*64+lane)*8 + j holds
// Bmat[k=kk*32+(lane>>4)*8+j][n=bn*16+(lane&15)], Bmat = [Wz_eff | Wh_eff].
__global__ __launch_bounds__(256) void wprep_kernel(
    const float* __restrict__ Wz, const float* __restrict__ Wh,
    unsigned short* __restrict__ wbf) {
    int idx = blockIdx.x * 256 + threadIdx.x;
    if (idx >= 12288) return;
    int j = idx & 7, ln = (idx >> 3) & 63, bn = (idx >> 9) & 7, kk = idx >> 12;
    int k = kk * 32 + (ln >> 4) * 8 + j;
    int n = bn * 16 + (ln & 15);
    int slab = k >> 5, c = k & 31;
    const float* W = (n < 64) ? Wz : Wh;
    int o = n & 63;
    float v;
    if (slab == 0)      v = W[c * 64 + o] + W[(2 * 96 + c) * 64 + o];
    else if (slab == 1) v = W[(96 + c) * 64 + o];
    else                v = W[(3 * 96 + c) * 64 + o];
    wbf[idx] = f2bf(v);
}

// 0b. x -> bf16 copy (unscaled, single 3.2 MB array; fits per-XCD L2)
__global__ __launch_bounds__(256) void xconv_kernel(
    const float4* __restrict__ x4, ushort4* __restrict__ xsb) {
    int i = blockIdx.x * 256 + threadIdx.x;
    if (i >= N_NODES * 8) return;
    float4 v = x4[i];
    ushort4 o;
    o.x = f2bf(v.x); o.y = f2bf(v.y); o.z = f2bf(v.z); o.w = f2bf(v.w);
    xsb[i] = o;
}

// 1. per-chunk coarse histograms, both dirs (LDS atomics; fully writes cntG)
__global__ __launch_bounds__(512) void hist_kernel(const int* __restrict__ ei,
                                                   int* __restrict__ cntG) {
    __shared__ int h[2 * NBIN];
    int tid = threadIdx.x;
    for (int i = tid; i < 2 * NBIN; i += 512) h[i] = 0;
    __syncthreads();
    int e0 = blockIdx.x * CHUNK;
    int e1 = min(e0 + CHUNK, N_EDGES);
    for (int e = e0 + tid; e < e1; e += 512) {
        int r = ei[e];
        int c = ei[N_EDGES + e];
        atomicAdd(&h[c >> BIN_SHIFT], 1);           // dir0: group by col
        atomicAdd(&h[NBIN + (r >> BIN_SHIFT)], 1);  // dir1: group by row
    }
    __syncthreads();
    for (int i = tid; i < 2 * NBIN; i += 512) cntG[i * NCHK + blockIdx.x] = h[i];
}

// ---- 3-phase exclusive scan over cntG ----
__global__ __launch_bounds__(256) void scan_partial_kernel(
    const int4* __restrict__ cnt4, int* __restrict__ blksum, int n4) {
    __shared__ int s[256];
    int t = threadIdx.x;
    int base4 = blockIdx.x * 1024 + t * 4;
    int total = 0;
#pragma unroll
    for (int j = 0; j < 4; ++j) {
        int idx = base4 + j;
        if (idx < n4) {
            int4 v = cnt4[idx];
            total += v.x + v.y + v.z + v.w;
        }
    }
    s[t] = total;
    __syncthreads();
    for (int off = 128; off > 0; off >>= 1) {
        if (t < off) s[t] += s[t + off];
        __syncthreads();
    }
    if (t == 0) blksum[blockIdx.x] = s[0];
}

__global__ __launch_bounds__(256) void scan_blocksum_kernel(int* __restrict__ blksum, int nb) {
    __shared__ int s[256];
    int t = threadIdx.x;
    int v = (t < nb) ? blksum[t] : 0;
    s[t] = v;
    __syncthreads();
    for (int off = 1; off < 256; off <<= 1) {
        int u = (t >= off) ? s[t - off] : 0;
        __syncthreads();
        s[t] += u;
        __syncthreads();
    }
    if (t < nb) blksum[t] = s[t] - v;  // exclusive
}

__global__ __launch_bounds__(256) void scan_final_kernel(
    int4* __restrict__ cnt4, const int* __restrict__ blksum, int n4) {
    __shared__ int s[256];
    int t = threadIdx.x;
    int base4 = blockIdx.x * 1024 + t * 4;
    int4 vals[4];
    int total = 0;
#pragma unroll
    for (int j = 0; j < 4; ++j) {
        int idx = base4 + j;
        vals[j] = (idx < n4) ? cnt4[idx] : make_int4(0, 0, 0, 0);
        total += vals[j].x + vals[j].y + vals[j].z + vals[j].w;
    }
    s[t] = total;
    __syncthreads();
    for (int off = 1; off < 256; off <<= 1) {
        int u = (t >= off) ? s[t - off] : 0;
        __syncthreads();
        s[t] += u;
        __syncthreads();
    }
    int run = blksum[blockIdx.x] + s[t] - total;
#pragma unroll
    for (int j = 0; j < 4; ++j) {
        int idx = base4 + j;
        int4 v = vals[j];
        int4 o;
        o.x = run; run += v.x;
        o.y = run; run += v.y;
        o.z = run; run += v.z;
        o.w = run; run += v.w;
        if (idx < n4) cnt4[idx] = o;
    }
}

// 3. COALESCED partition (round-12 design). One block = one (dir, chunk);
// LDS re-staging makes the global write-out coalesced.
__global__ __launch_bounds__(512) void partition_kernel(
    const int* __restrict__ ei, const float* __restrict__ ew,
    const int* __restrict__ cntG, int2* __restrict__ binned) {
    __shared__ int2 stg[CHUNK];      // 32 KB
    __shared__ int hist[NBIN];       // counts -> (after scan) local starts
    __shared__ int gStart[NBIN];
    __shared__ int sc[512];
    int tid = threadIdx.x;
    int dir = (blockIdx.x >= NCHK) ? 1 : 0;
    int chunk = blockIdx.x - dir * NCHK;

    for (int i = tid; i < NBIN; i += 512) hist[i] = 0;
    __syncthreads();

    int e0 = chunk * CHUNK;
    int n_e = min(CHUNK, N_EDGES - e0);
    int binv[8], rankv[8];
    int2 pay[8];
#pragma unroll
    for (int j = 0; j < 8; ++j) {
        int idx = tid + j * 512;
        if (idx < n_e) {
            int e = e0 + idx;
            int r = ei[e];
            int c = ei[N_EDGES + e];
            int dst = dir ? r : c;
            int src = dir ? c : r;
            int b = dst >> BIN_SHIFT;
            binv[j] = b;
            rankv[j] = atomicAdd(&hist[b], 1);
            pay[j] = make_int2((int)(((unsigned)b << 23) | ((unsigned)(dst & 127) << 16) |
                                     (unsigned)src),
                               __float_as_int(ew[e]));
        } else {
            binv[j] = -1;
        }
    }
    __syncthreads();
    int v = (tid < NBIN) ? hist[tid] : 0;
    sc[tid] = v;
    __syncthreads();
    for (int off = 1; off < 512; off <<= 1) {
        int u = (tid >= off) ? sc[tid - off] : 0;
        __syncthreads();
        sc[tid] += u;
        __syncthreads();
    }
    if (tid < NBIN) {
        hist[tid] = sc[tid] - v;  // local start
        gStart[tid] = cntG[(dir * NBIN + tid) * NCHK + chunk];
    }
    __syncthreads();
#pragma unroll
    for (int j = 0; j < 8; ++j)
        if (binv[j] >= 0) stg[hist[binv[j]] + rankv[j]] = pay[j];
    __syncthreads();
    for (int p = tid; p < n_e; p += 512) {
        int2 v2 = stg[p];
        int b = (int)(((unsigned)v2.x) >> 23);
        int gpos = gStart[b] + (p - hist[b]);
        binned[gpos] = make_int2(v2.x & 0x7FFFFF, v2.y);
    }
}

__device__ __forceinline__ void bin_range(const int* cntG, int b, int& lo, int& hi) {
    lo = cntG[b * NCHK];
    hi = (b + 1 < 2 * NBIN) ? cntG[(b + 1) * NCHK] : 2 * N_EDGES;
}

// 4. per-bin degrees + per-node counts (both dirs, one launch); linear stream.
__global__ __launch_bounds__(512) void bindeg_kernel(
    const int* __restrict__ cntG, const int2* __restrict__ binned,
    int* __restrict__ binCnt, float* __restrict__ ws_f) {
    __shared__ float wsum[128];
    __shared__ int cnt[128];
    int tid = threadIdx.x;
    int b = blockIdx.x;
    int dir = (b >= NBIN) ? 1 : 0;
    if (tid < 128) { wsum[tid] = 0.f; cnt[tid] = 0; }
    __syncthreads();
    int lo, hi;
    bin_range(cntG, b, lo, hi);
    for (int p = lo + tid; p < hi; p += 512) {
        int2 v = binned[p];
        int d = v.x >> 16;
        atomicAdd(&cnt[d], 1);
        atomicAdd(&wsum[d], __int_as_float(v.y));
    }
    __syncthreads();
    if (tid < 128) {
        binCnt[b * 128 + tid] = cnt[tid];
        int node = (b - dir * NBIN) * 128 + tid;
        if (node < N_NODES) {
            float s = wsum[tid];
            float* rdeg = ws_f + (dir == 0 ? WS_RDEG_IN : WS_RDEG_OUT);
            rdeg[node] = (s != 0.f) ? (1.f / s) : 0.f;
        }
    }
}

// 5. fused in-LDS binsort + register gather, BOTH dirs in one launch.
// coef = w * rdeg[src]; x rows bf16 (64 B) from the single 3.2 MB xsb.
__global__ __launch_bounds__(512) void fgather_kernel(
    const ushort4* __restrict__ xsb, const int* __restrict__ cntG,
    const int* __restrict__ binCnt, const int2* __restrict__ binned,
    float* __restrict__ ws_f) {
    __shared__ int2 s_edge[FG_CAP];  // 36.9 KB
    __shared__ int s_off[129];
    __shared__ int s_cur[128];
    __shared__ int sc[128];
    int tid = threadIdx.x;
    int b = blockIdx.x;
    int dir = (b >= NBIN) ? 1 : 0;
    int bin = b - dir * NBIN;

    // A: exclusive scan of 128 counts
    int v = (tid < 128) ? binCnt[b * 128 + tid] : 0;
    if (tid < 128) sc[tid] = v;
    __syncthreads();
    for (int off = 1; off < 128; off <<= 1) {
        int u = (tid < 128 && tid >= off) ? sc[tid - off] : 0;
        __syncthreads();
        if (tid < 128) sc[tid] += u;
        __syncthreads();
    }
    if (tid < 128) {
        s_off[tid] = sc[tid] - v;
        s_cur[tid] = sc[tid] - v;
    }
    if (tid == 127) s_off[128] = sc[127];
    __syncthreads();

    // B: scatter into LDS sorted order (linear read of binned)
    int lo, hi;
    bin_range(cntG, b, lo, hi);
    int n_e = hi - lo;
    for (int p = tid; p < n_e; p += 512) {
        int2 ev = binned[lo + p];
        int rk = atomicAdd(&s_cur[ev.x >> 16], 1);
        if (rk < FG_CAP) s_edge[rk] = ev;
    }
    __syncthreads();

    // C: register-accumulating gather; coef = w * rdeg[src]
    const float* rdeg = ws_f + (dir == 0 ? WS_RDEG_OUT : WS_RDEG_IN);
    ushort4* outp = (ushort4*)(ws_f + (dir == 0 ? WS_TXO : WS_TXI));
    int lane = tid & 7;
#pragma unroll
    for (int it = 0; it < 2; ++it) {
        int nl = it * 64 + (tid >> 3);
        int p = s_off[nl], end = s_off[nl + 1];
        float4 acc = make_float4(0.f, 0.f, 0.f, 0.f);
        for (; p + 1 < end; p += 2) {
            int2 v0 = s_edge[p], v1 = s_edge[p + 1];
            int s0 = v0.x & 0xffff, s1 = v1.x & 0xffff;
            float c0 = __int_as_float(v0.y) * rdeg[s0];
            float c1 = __int_as_float(v1.y) * rdeg[s1];
            ushort4 a = xsb[s0 * 8 + lane];
            ushort4 bb = xsb[s1 * 8 + lane];
            acc.x += c0 * bf2f(a.x) + c1 * bf2f(bb.x);
            acc.y += c0 * bf2f(a.y) + c1 * bf2f(bb.y);
            acc.z += c0 * bf2f(a.z) + c1 * bf2f(bb.z);
            acc.w += c0 * bf2f(a.w) + c1 * bf2f(bb.w);
        }
        if (p < end) {
            int2 v0 = s_edge[p];
            int s0 = v0.x & 0xffff;
            float c0 = __int_as_float(v0.y) * rdeg[s0];
            ushort4 a = xsb[s0 * 8 + lane];
            acc.x += c0 * bf2f(a.x);
            acc.y += c0 * bf2f(a.y);
            acc.z += c0 * bf2f(a.z);
            acc.w += c0 * bf2f(a.w);
        }
        int node = bin * 128 + nl;
        if (node < N_NODES) {
            ushort4 o;
            o.x = f2bf(acc.x); o.y = f2bf(acc.y);
            o.z = f2bf(acc.z); o.w = f2bf(acc.w);
            outp[node * 8 + lane] = o;
        }
    }
}

// 6. Dense epilogue via bf16 MFMA (unchanged from round 13).
#define DN_GROUP 64
#define DN_BLOCKS ((N_NODES + DN_GROUP - 1) / DN_GROUP)  // 782
__global__ __launch_bounds__(256) void dense_kernel(
    const float4* __restrict__ x4,
    const int4* __restrict__ txo_b, const int4* __restrict__ txi_b,
    const unsigned short* __restrict__ wbf,
    const float* __restrict__ bz, const float* __restrict__ bh,
    const float* __restrict__ Wlin, const float* __restrict__ blin,
    float* __restrict__ out) {
    __shared__ unsigned short sA[64 * 104];  // 13.0 KB
    __shared__ unsigned short sB[12288];     // 24.0 KB

    int tid = threadIdx.x;
    int lane = tid & 63, w = tid >> 6;
    int lm = lane & 15, quad = lane >> 4;

    for (int idx = tid; idx < 3072; idx += 256)
        *(ushort4*)&sB[idx * 4] = ((const ushort4*)wbf)[idx];

    int node0 = blockIdx.x * DN_GROUP;
    for (int idx = tid; idx < 64 * 8; idx += 256) {
        int nl = idx >> 3, q = idx & 7;
        int node = node0 + nl;
        float4 v = (node < N_NODES) ? x4[node * 8 + q]
                                    : make_float4(0.f, 0.f, 0.f, 0.f);
        ushort4 bq;
        bq.x = f2bf(v.x); bq.y = f2bf(v.y); bq.z = f2bf(v.z); bq.w = f2bf(v.w);
        *(ushort4*)&sA[nl * 104 + q * 4] = bq;
    }
    for (int idx = tid; idx < 64 * 8; idx += 256) {
        int nl = idx >> 3, q = idx & 7;
        int node = node0 + nl;
        int4 v = make_int4(0, 0, 0, 0);
        if (node < N_NODES)
            v = (q < 4) ? txo_b[node * 4 + q] : txi_b[node * 4 + (q - 4)];
        *(int4*)&sA[nl * 104 + 32 + q * 8] = v;
    }

    float bzv[4], bhv[4], wlv[4];
#pragma unroll
    for (int bn = 0; bn < 4; ++bn) {
        int o = lm + 16 * bn;
        bzv[bn] = bz[o]; bhv[bn] = bh[o]; wlv[bn] = Wlin[o];
    }
    float bl = blin[0];
    __syncthreads();

    f32x4 acc[8];
#pragma unroll
    for (int bn = 0; bn < 4; ++bn) {
        acc[bn]     = (f32x4){bzv[bn], bzv[bn], bzv[bn], bzv[bn]};
        acc[bn + 4] = (f32x4){bhv[bn], bhv[bn], bhv[bn], bhv[bn]};
    }
#pragma unroll
    for (int kk = 0; kk < 3; ++kk) {
        bf16x8 af = *(const bf16x8*)&sA[(w * 16 + lm) * 104 + kk * 32 + quad * 8];
#pragma unroll
        for (int bn = 0; bn < 8; ++bn) {
            bf16x8 bf = *(const bf16x8*)&sB[((kk * 8 + bn) * 64 + lane) * 8];
            acc[bn] = __builtin_amdgcn_mfma_f32_16x16x32_bf16(af, bf, acc[bn], 0, 0, 0);
        }
    }

    float partial[4] = {0.f, 0.f, 0.f, 0.f};
#pragma unroll
    for (int bn = 0; bn < 4; ++bn) {
#pragma unroll
        for (int reg = 0; reg < 4; ++reg) {
            float az = acc[bn][reg], ah = acc[bn + 4][reg];
            float z = 1.f / (1.f + __expf(-az));
            float ht = 1.f - 2.f / (__expf(2.f * ah) + 1.f);
            partial[reg] += fmaxf((1.f - z) * ht, 0.f) * wlv[bn];
        }
    }
#pragma unroll
    for (int reg = 0; reg < 4; ++reg) {
        float s = partial[reg];
        s += __shfl_xor(s, 1, 64);
        s += __shfl_xor(s, 2, 64);
        s += __shfl_xor(s, 4, 64);
        s += __shfl_xor(s, 8, 64);
        if (lm == 0) {
            int node = node0 + w * 16 + quad * 4 + reg;
            if (node < N_NODES) out[node] = s + bl;
        }
    }
}

extern "C" void kernel_launch(void* const* d_in, const int* in_sizes, int n_in,
                              void* d_out, int out_size, void* d_ws, size_t ws_size,
                              hipStream_t stream) {
    const float* x = (const float*)d_in[0];
    const int* ei = (const int*)d_in[1];
    const float* ew = (const float*)d_in[2];
    const float* Wz = (const float*)d_in[3];
    const float* bz = (const float*)d_in[4];
    // d_in[5]=Wr, d_in[6]=br dead: H0==0 makes the reset gate a no-op
    const float* Wh = (const float*)d_in[7];
    const float* bh = (const float*)d_in[8];
    const float* Wlin = (const float*)d_in[9];
    const float* blin = (const float*)d_in[10];
    float* out = (float*)d_out;
    float* wf = (float*)d_ws;
    int* wi = (int*)d_ws;
    int2* binned = (int2*)(wi + WS_BINNED);

    // 0. weight prep (bf16, B-fragment order) + bf16 x copy
    wprep_kernel<<<48, 256, 0, stream>>>(Wz, Wh, (unsigned short*)(wi + WS_WBF));
    xconv_kernel<<<(N_NODES * 8 + 255) / 256, 256, 0, stream>>>(
        (const float4*)x, (ushort4*)(wi + WS_XSB));
    // 1. coarse per-chunk histograms, both dirs
    hist_kernel<<<NCHK, 512, 0, stream>>>(ei, wi + WS_CNTG);
    // 2. exclusive scan of the (dir,bin,chunk) count matrix
    scan_partial_kernel<<<SCAN_BLOCKS, 256, 0, stream>>>(
        (const int4*)(wi + WS_CNTG), wi + WS_BLKSUM, CNTG_N4);
    scan_blocksum_kernel<<<1, 256, 0, stream>>>(wi + WS_BLKSUM, SCAN_BLOCKS);
    scan_final_kernel<<<SCAN_BLOCKS, 256, 0, stream>>>(
        (int4*)(wi + WS_CNTG), wi + WS_BLKSUM, CNTG_N4);
    // 3. coalesced partition (one block per dir x chunk; LDS re-staging)
    partition_kernel<<<2 * NCHK, 512, 0, stream>>>(ei, ew, wi + WS_CNTG, binned);
    // 4. per-bin degrees + saved node counts (both dirs, linear stream)
    bindeg_kernel<<<2 * NBIN, 512, 0, stream>>>(
        wi + WS_CNTG, binned, wi + WS_BINCNT, wf);
    // 5. fused binsort+gather, both dirs -> bf16 Tx_o / Tx_i
    fgather_kernel<<<2 * NBIN, 512, 0, stream>>>(
        (const ushort4*)(wi + WS_XSB), wi + WS_CNTG, wi + WS_BINCNT, binned, wf);
    // 6. MFMA dense epilogue (bf16 Tx inputs)
    dense_kernel<<<DN_BLOCKS, 256, 0, stream>>>(
        (const float4*)x, (const int4*)(wi + WS_TXO), (const int4*)(wi + WS_TXI),
        (const unsigned short*)(wi + WS_WBF), bz, bh, Wlin, blin, out);
}

// Round 15
// 196.120 us; speedup vs baseline: 1.8861x; 1.0099x over previous
//
#include <hip/hip_runtime.h>
#include <math.h>

#define N_NODES 50000
#define N_EDGES 1600000
#define IN_CH 32
#define HID 64

// ---------------- pipeline (10 dispatches, zero global atomics) ------------
// wprep -> xconv -> hist -> scan(3) -> partition -> bindeg -> fgather(both
// dirs) -> dense(MFMA)
// Round-15 reshape (fgather was latency/occupancy-bound: 44% occ, 22% VALU):
//  - bins of 64 nodes (NBIN=782/dir); fgather blocks 256 thr / 20.5 KB LDS
//    -> 7 blocks/CU (~2x wave supply), 1564 blocks (~6/CU, finer tail)
//  - coef = w*rdeg[src] computed in phase B (off C's critical chain)
//  - C phase 4-way unrolled (4 independent xsb loads in flight)
//  - partition CHUNK=8192 keeps write runs at ~10.4 edges (>= 64 B line,
//    the R12 coalescing lesson) despite narrower bins
#define NBIN 782
#define BIN_SHIFT 6
#define CHUNK 8192
#define NCHK ((N_EDGES + CHUNK - 1) / CHUNK)   // 196
#define CNTG_N (2 * NBIN * NCHK)               // 306544 (divisible by 4)
#define CNTG_N4 (CNTG_N / 4)                   // 76636
#define SCAN_BLOCKS ((CNTG_N4 + 1023) / 1024)  // 75
#define FG_CAP 2560   // bin capacity: mean 2046 + ~11 sigma (Binomial)

// ---------------- workspace layout (int element offsets into d_ws)
#define WS_RDEG_OUT 0          // 50000 f (row-degree reciprocals, from dir1 bins)
#define WS_RDEG_IN  50000      // 50000 f (col-degree reciprocals, from dir0 bins)
#define WS_CNTG     100000     // 306544 i ((dir,bin,chunk) counts; scanned in place)
#define WS_BLKSUM   406548     // 128 i
#define WS_WBF      406676     // 6144 i = 12288 ushort (bf16 weights, B-frag order)
#define WS_BINCNT   412820     // 100096 i (1564 bins x 64 per-node counts)
#define WS_XSB      512916     // 800000 i = 1.6M ushort (bf16 x, unscaled)
#define WS_TXO      1312916    // 800000 i (bf16 Tx_o, 50000 x 32)
#define WS_TXI      2112916    // 800000 i (bf16 Tx_i)
#define WS_BINNED   2912916    // int2[3.2M] = 6400000 i
#define WS_END      9312916    // 37.3 MB (ws is 256 MiB)

typedef __attribute__((ext_vector_type(8))) short bf16x8;
typedef __attribute__((ext_vector_type(4))) float f32x4;

__device__ __forceinline__ unsigned short f2bf(float f) {  // RNE fp32 -> bf16
    unsigned int u = __float_as_uint(f);
    return (unsigned short)((u + 0x7fffu + ((u >> 16) & 1u)) >> 16);
}
__device__ __forceinline__ float bf2f(unsigned short b) {
    return __uint_as_float((unsigned int)b << 16);
}

// 0. weight prep: combine diffusion slabs, bf16-convert, store in the EXACT
// B-fragment order used by dense (see dense_kernel header).
__global__ __launch_bounds__(256) void wprep_kernel(
    const float* __restrict__ Wz, const float* __restrict__ Wh,
    unsigned short* __restrict__ wbf) {
    int idx = blockIdx.x * 256 + threadIdx.x;
    if (idx >= 12288) return;
    int j = idx & 7, ln = (idx >> 3) & 63, bn = (idx >> 9) & 7, kk = idx >> 12;
    int k = kk * 32 + (ln >> 4) * 8 + j;
    int n = bn * 16 + (ln & 15);
    int slab = k >> 5, c = k & 31;
    const float* W = (n < 64) ? Wz : Wh;
    int o = n & 63;
    float v;
    if (slab == 0)      v = W[c * 64 + o] + W[(2 * 96 + c) * 64 + o];
    else if (slab == 1) v = W[(96 + c) * 64 + o];
    else                v = W[(3 * 96 + c) * 64 + o];
    wbf[idx] = f2bf(v);
}

// 0b. x -> bf16 copy (unscaled, single 3.2 MB array; fits per-XCD L2)
__global__ __launch_bounds__(256) void xconv_kernel(
    const float4* __restrict__ x4, ushort4* __restrict__ xsb) {
    int i = blockIdx.x * 256 + threadIdx.x;
    if (i >= N_NODES * 8) return;
    float4 v = x4[i];
    ushort4 o;
    o.x = f2bf(v.x); o.y = f2bf(v.y); o.z = f2bf(v.z); o.w = f2bf(v.w);
    xsb[i] = o;
}

// 1. per-chunk coarse histograms, both dirs (LDS atomics; fully writes cntG)
__global__ __launch_bounds__(512) void hist_kernel(const int* __restrict__ ei,
                                                   int* __restrict__ cntG) {
    __shared__ int h[2 * NBIN];
    int tid = threadIdx.x;
    for (int i = tid; i < 2 * NBIN; i += 512) h[i] = 0;
    __syncthreads();
    int e0 = blockIdx.x * CHUNK;
    int e1 = min(e0 + CHUNK, N_EDGES);
    for (int e = e0 + tid; e < e1; e += 512) {
        int r = ei[e];
        int c = ei[N_EDGES + e];
        atomicAdd(&h[c >> BIN_SHIFT], 1);           // dir0: group by col
        atomicAdd(&h[NBIN + (r >> BIN_SHIFT)], 1);  // dir1: group by row
    }
    __syncthreads();
    for (int i = tid; i < 2 * NBIN; i += 512) cntG[i * NCHK + blockIdx.x] = h[i];
}

// ---- 3-phase exclusive scan over cntG ----
__global__ __launch_bounds__(256) void scan_partial_kernel(
    const int4* __restrict__ cnt4, int* __restrict__ blksum, int n4) {
    __shared__ int s[256];
    int t = threadIdx.x;
    int base4 = blockIdx.x * 1024 + t * 4;
    int total = 0;
#pragma unroll
    for (int j = 0; j < 4; ++j) {
        int idx = base4 + j;
        if (idx < n4) {
            int4 v = cnt4[idx];
            total += v.x + v.y + v.z + v.w;
        }
    }
    s[t] = total;
    __syncthreads();
    for (int off = 128; off > 0; off >>= 1) {
        if (t < off) s[t] += s[t + off];
        __syncthreads();
    }
    if (t == 0) blksum[blockIdx.x] = s[0];
}

__global__ __launch_bounds__(256) void scan_blocksum_kernel(int* __restrict__ blksum, int nb) {
    __shared__ int s[256];
    int t = threadIdx.x;
    int v = (t < nb) ? blksum[t] : 0;
    s[t] = v;
    __syncthreads();
    for (int off = 1; off < 256; off <<= 1) {
        int u = (t >= off) ? s[t - off] : 0;
        __syncthreads();
        s[t] += u;
        __syncthreads();
    }
    if (t < nb) blksum[t] = s[t] - v;  // exclusive
}

__global__ __launch_bounds__(256) void scan_final_kernel(
    int4* __restrict__ cnt4, const int* __restrict__ blksum, int n4) {
    __shared__ int s[256];
    int t = threadIdx.x;
    int base4 = blockIdx.x * 1024 + t * 4;
    int4 vals[4];
    int total = 0;
#pragma unroll
    for (int j = 0; j < 4; ++j) {
        int idx = base4 + j;
        vals[j] = (idx < n4) ? cnt4[idx] : make_int4(0, 0, 0, 0);
        total += vals[j].x + vals[j].y + vals[j].z + vals[j].w;
    }
    s[t] = total;
    __syncthreads();
    for (int off = 1; off < 256; off <<= 1) {
        int u = (t >= off) ? s[t - off] : 0;
        __syncthreads();
        s[t] += u;
        __syncthreads();
    }
    int run = blksum[blockIdx.x] + s[t] - total;
#pragma unroll
    for (int j = 0; j < 4; ++j) {
        int idx = base4 + j;
        int4 v = vals[j];
        int4 o;
        o.x = run; run += v.x;
        o.y = run; run += v.y;
        o.z = run; run += v.z;
        o.w = run; run += v.w;
        if (idx < n4) cnt4[idx] = o;
    }
}

// 3. COALESCED partition. One block = one (dir, chunk of 8192); LDS
// re-staging makes the global write-out coalesced (runs ~10.4 edges).
// 782-bin local scan done as a 391-pair Hillis-Steele.
__global__ __launch_bounds__(512) void partition_kernel(
    const int* __restrict__ ei, const float* __restrict__ ew,
    const int* __restrict__ cntG, int2* __restrict__ binned) {
    __shared__ int2 stg[CHUNK];      // 64 KB
    __shared__ int hist[NBIN];
    __shared__ int lst[NBIN];        // local bin starts
    __shared__ int gStart[NBIN];
    __shared__ int sc[512];
    int tid = threadIdx.x;
    int dir = (blockIdx.x >= NCHK) ? 1 : 0;
    int chunk = blockIdx.x - dir * NCHK;

    for (int i = tid; i < NBIN; i += 512) hist[i] = 0;
    __syncthreads();

    int e0 = chunk * CHUNK;
    int n_e = min(CHUNK, N_EDGES - e0);
    int binv[16], rankv[16];
    int2 pay[16];
#pragma unroll
    for (int j = 0; j < 16; ++j) {
        int idx = tid + j * 512;
        if (idx < n_e) {
            int e = e0 + idx;
            int r = ei[e];
            int c = ei[N_EDGES + e];
            int dst = dir ? r : c;
            int src = dir ? c : r;
            int b = dst >> BIN_SHIFT;
            binv[j] = b;
            rankv[j] = atomicAdd(&hist[b], 1);
            pay[j] = make_int2((int)(((unsigned)b << 22) | ((unsigned)(dst & 63) << 16) |
                                     (unsigned)src),
                               __float_as_int(ew[e]));
        } else {
            binv[j] = -1;
        }
    }
    __syncthreads();
    // pair-scan: 391 pairs cover 782 bins
    int ps = (tid < 391) ? (hist[2 * tid] + hist[2 * tid + 1]) : 0;
    sc[tid] = ps;
    __syncthreads();
    for (int off = 1; off < 512; off <<= 1) {
        int u = (tid >= off) ? sc[tid - off] : 0;
        __syncthreads();
        sc[tid] += u;
        __syncthreads();
    }
    if (tid < 391) {
        int pref = sc[tid] - ps;  // exclusive pair prefix
        lst[2 * tid] = pref;
        lst[2 * tid + 1] = pref + hist[2 * tid];
    }
    for (int i = tid; i < NBIN; i += 512)
        gStart[i] = cntG[(dir * NBIN + i) * NCHK + chunk];
    __syncthreads();
#pragma unroll
    for (int j = 0; j < 16; ++j)
        if (binv[j] >= 0) stg[lst[binv[j]] + rankv[j]] = pay[j];
    __syncthreads();
    for (int p = tid; p < n_e; p += 512) {
        int2 v2 = stg[p];
        int b = (int)(((unsigned)v2.x) >> 22);
        int gpos = gStart[b] + (p - lst[b]);
        binned[gpos] = make_int2(v2.x & 0x3FFFFF, v2.y);
    }
}

__device__ __forceinline__ void bin_range(const int* cntG, int b, int& lo, int& hi) {
    lo = cntG[b * NCHK];
    hi = (b + 1 < 2 * NBIN) ? cntG[(b + 1) * NCHK] : 2 * N_EDGES;
}

// 4. per-bin degrees + per-node counts (both dirs, one launch); linear stream.
__global__ __launch_bounds__(256) void bindeg_kernel(
    const int* __restrict__ cntG, const int2* __restrict__ binned,
    int* __restrict__ binCnt, float* __restrict__ ws_f) {
    __shared__ float wsum[64];
    __shared__ int cnt[64];
    int tid = threadIdx.x;
    int b = blockIdx.x;
    int dir = (b >= NBIN) ? 1 : 0;
    if (tid < 64) { wsum[tid] = 0.f; cnt[tid] = 0; }
    __syncthreads();
    int lo, hi;
    bin_range(cntG, b, lo, hi);
    for (int p = lo + tid; p < hi; p += 256) {
        int2 v = binned[p];
        int d = v.x >> 16;  // dstLocal (6 bits; bin bits stripped by partition)
        atomicAdd(&cnt[d], 1);
        atomicAdd(&wsum[d], __int_as_float(v.y));
    }
    __syncthreads();
    if (tid < 64) {
        binCnt[b * 64 + tid] = cnt[tid];
        int node = (b - dir * NBIN) * 64 + tid;
        if (node < N_NODES) {
            float s = wsum[tid];
            float* rdeg = ws_f + (dir == 0 ? WS_RDEG_IN : WS_RDEG_OUT);
            rdeg[node] = (s != 0.f) ? (1.f / s) : 0.f;
        }
    }
}

// 5. fused in-LDS binsort + register gather, both dirs, 256-thr blocks.
// B: coef = w*rdeg[src] computed here (off C's chain); s_edge = (src, coef).
// C: 32 groups x 8 lanes x 2 iterations, 4-way unrolled.
__global__ __launch_bounds__(256) void fgather_kernel(
    const ushort4* __restrict__ xsb, const int* __restrict__ cntG,
    const int* __restrict__ binCnt, const int2* __restrict__ binned,
    float* __restrict__ ws_f) {
    __shared__ int2 s_edge[FG_CAP];  // 20.5 KB -> 7 blocks/CU
    __shared__ int s_off[65];
    __shared__ int s_cur[64];
    __shared__ int sc[64];
    int tid = threadIdx.x;
    int b = blockIdx.x;
    int dir = (b >= NBIN) ? 1 : 0;
    int bin = b - dir * NBIN;

    // A: exclusive scan of 64 counts
    int v = (tid < 64) ? binCnt[b * 64 + tid] : 0;
    if (tid < 64) sc[tid] = v;
    __syncthreads();
    for (int off = 1; off < 64; off <<= 1) {
        int u = (tid < 64 && tid >= off) ? sc[tid - off] : 0;
        __syncthreads();
        if (tid < 64) sc[tid] += u;
        __syncthreads();
    }
    if (tid < 64) {
        s_off[tid] = sc[tid] - v;
        s_cur[tid] = sc[tid] - v;
    }
    if (tid == 63) s_off[64] = sc[63];
    __syncthreads();

    // B: stream bin edges; fold rdeg into coef; scatter (src, coef) sorted
    const float* rdeg = ws_f + (dir == 0 ? WS_RDEG_OUT : WS_RDEG_IN);
    int lo, hi;
    bin_range(cntG, b, lo, hi);
    int n_e = hi - lo;
    for (int p = tid; p < n_e; p += 256) {
        int2 ev = binned[lo + p];
        int src = ev.x & 0xffff;
        float coef = __int_as_float(ev.y) * rdeg[src];
        int rk = atomicAdd(&s_cur[ev.x >> 16], 1);
        if (rk < FG_CAP) s_edge[rk] = make_int2(src, __float_as_int(coef));
    }
    __syncthreads();

    // C: register-accumulating gather, 4-way unrolled
    ushort4* outp = (ushort4*)(ws_f + (dir == 0 ? WS_TXO : WS_TXI));
    int lane = tid & 7;
#pragma unroll
    for (int it = 0; it < 2; ++it) {
        int nl = it * 32 + (tid >> 3);
        int p = s_off[nl], end = s_off[nl + 1];
        float4 acc = make_float4(0.f, 0.f, 0.f, 0.f);
        for (; p + 3 < end; p += 4) {
            int2 v0 = s_edge[p], v1 = s_edge[p + 1];
            int2 v2 = s_edge[p + 2], v3 = s_edge[p + 3];
            ushort4 a0 = xsb[v0.x * 8 + lane];
            ushort4 a1 = xsb[v1.x * 8 + lane];
            ushort4 a2 = xsb[v2.x * 8 + lane];
            ushort4 a3 = xsb[v3.x * 8 + lane];
            float c0 = __int_as_float(v0.y), c1 = __int_as_float(v1.y);
            float c2 = __int_as_float(v2.y), c3 = __int_as_float(v3.y);
            acc.x += c0 * bf2f(a0.x) + c1 * bf2f(a1.x) + c2 * bf2f(a2.x) + c3 * bf2f(a3.x);
            acc.y += c0 * bf2f(a0.y) + c1 * bf2f(a1.y) + c2 * bf2f(a2.y) + c3 * bf2f(a3.y);
            acc.z += c0 * bf2f(a0.z) + c1 * bf2f(a1.z) + c2 * bf2f(a2.z) + c3 * bf2f(a3.z);
            acc.w += c0 * bf2f(a0.w) + c1 * bf2f(a1.w) + c2 * bf2f(a2.w) + c3 * bf2f(a3.w);
        }
        for (; p < end; ++p) {
            int2 v0 = s_edge[p];
            float c0 = __int_as_float(v0.y);
            ushort4 a = xsb[v0.x * 8 + lane];
            acc.x += c0 * bf2f(a.x);
            acc.y += c0 * bf2f(a.y);
            acc.z += c0 * bf2f(a.z);
            acc.w += c0 * bf2f(a.w);
        }
        int node = bin * 64 + nl;
        if (node < N_NODES) {
            ushort4 o;
            o.x = f2bf(acc.x); o.y = f2bf(acc.y);
            o.z = f2bf(acc.z); o.w = f2bf(acc.w);
            outp[node * 8 + lane] = o;
        }
    }
}

// 6. Dense epilogue via bf16 MFMA (unchanged since round 11/13).
// Per block: C[64 x 128 (z|h)] = A[64x96]_bf16 x B[96x128]_bf16 + bias.
// A-frag: A[m=lane&15][k=quad*8+j]; B-frag: B[k=quad*8+j][n=lane&15];
// C/D: col=lane&15, row=quad*4+reg (m89/m91-verified).
#define DN_GROUP 64
#define DN_BLOCKS ((N_NODES + DN_GROUP - 1) / DN_GROUP)  // 782
__global__ __launch_bounds__(256) void dense_kernel(
    const float4* __restrict__ x4,
    const int4* __restrict__ txo_b, const int4* __restrict__ txi_b,
    const unsigned short* __restrict__ wbf,
    const float* __restrict__ bz, const float* __restrict__ bh,
    const float* __restrict__ Wlin, const float* __restrict__ blin,
    float* __restrict__ out) {
    __shared__ unsigned short sA[64 * 104];  // 13.0 KB
    __shared__ unsigned short sB[12288];     // 24.0 KB

    int tid = threadIdx.x;
    int lane = tid & 63, w = tid >> 6;
    int lm = lane & 15, quad = lane >> 4;

    for (int idx = tid; idx < 3072; idx += 256)
        *(ushort4*)&sB[idx * 4] = ((const ushort4*)wbf)[idx];

    int node0 = blockIdx.x * DN_GROUP;
    for (int idx = tid; idx < 64 * 8; idx += 256) {
        int nl = idx >> 3, q = idx & 7;
        int node = node0 + nl;
        float4 v = (node < N_NODES) ? x4[node * 8 + q]
                                    : make_float4(0.f, 0.f, 0.f, 0.f);
        ushort4 bq;
        bq.x = f2bf(v.x); bq.y = f2bf(v.y); bq.z = f2bf(v.z); bq.w = f2bf(v.w);
        *(ushort4*)&sA[nl * 104 + q * 4] = bq;
    }
    for (int idx = tid; idx < 64 * 8; idx += 256) {
        int nl = idx >> 3, q = idx & 7;
        int node = node0 + nl;
        int4 v = make_int4(0, 0, 0, 0);
        if (node < N_NODES)
            v = (q < 4) ? txo_b[node * 4 + q] : txi_b[node * 4 + (q - 4)];
        *(int4*)&sA[nl * 104 + 32 + q * 8] = v;
    }

    float bzv[4], bhv[4], wlv[4];
#pragma unroll
    for (int bn = 0; bn < 4; ++bn) {
        int o = lm + 16 * bn;
        bzv[bn] = bz[o]; bhv[bn] = bh[o]; wlv[bn] = Wlin[o];
    }
    float bl = blin[0];
    __syncthreads();

    f32x4 acc[8];
#pragma unroll
    for (int bn = 0; bn < 4; ++bn) {
        acc[bn]     = (f32x4){bzv[bn], bzv[bn], bzv[bn], bzv[bn]};
        acc[bn + 4] = (f32x4){bhv[bn], bhv[bn], bhv[bn], bhv[bn]};
    }
#pragma unroll
    for (int kk = 0; kk < 3; ++kk) {
        bf16x8 af = *(const bf16x8*)&sA[(w * 16 + lm) * 104 + kk * 32 + quad * 8];
#pragma unroll
        for (int bn = 0; bn < 8; ++bn) {
            bf16x8 bf = *(const bf16x8*)&sB[((kk * 8 + bn) * 64 + lane) * 8];
            acc[bn] = __builtin_amdgcn_mfma_f32_16x16x32_bf16(af, bf, acc[bn], 0, 0, 0);
        }
    }

    float partial[4] = {0.f, 0.f, 0.f, 0.f};
#pragma unroll
    for (int bn = 0; bn < 4; ++bn) {
#pragma unroll
        for (int reg = 0; reg < 4; ++reg) {
            float az = acc[bn][reg], ah = acc[bn + 4][reg];
            float z = 1.f / (1.f + __expf(-az));
            float ht = 1.f - 2.f / (__expf(2.f * ah) + 1.f);
            partial[reg] += fmaxf((1.f - z) * ht, 0.f) * wlv[bn];
        }
    }
#pragma unroll
    for (int reg = 0; reg < 4; ++reg) {
        float s = partial[reg];
        s += __shfl_xor(s, 1, 64);
        s += __shfl_xor(s, 2, 64);
        s += __shfl_xor(s, 4, 64);
        s += __shfl_xor(s, 8, 64);
        if (lm == 0) {
            int node = node0 + w * 16 + quad * 4 + reg;
            if (node < N_NODES) out[node] = s + bl;
        }
    }
}

extern "C" void kernel_launch(void* const* d_in, const int* in_sizes, int n_in,
                              void* d_out, int out_size, void* d_ws, size_t ws_size,
                              hipStream_t stream) {
    const float* x = (const float*)d_in[0];
    const int* ei = (const int*)d_in[1];
    const float* ew = (const float*)d_in[2];
    const float* Wz = (const float*)d_in[3];
    const float* bz = (const float*)d_in[4];
    // d_in[5]=Wr, d_in[6]=br dead: H0==0 makes the reset gate a no-op
    const float* Wh = (const float*)d_in[7];
    const float* bh = (const float*)d_in[8];
    const float* Wlin = (const float*)d_in[9];
    const float* blin = (const float*)d_in[10];
    float* out = (float*)d_out;
    float* wf = (float*)d_ws;
    int* wi = (int*)d_ws;
    int2* binned = (int2*)(wi + WS_BINNED);

    // 0. weight prep (bf16, B-frag order) + bf16 x copy
    wprep_kernel<<<48, 256, 0, stream>>>(Wz, Wh, (unsigned short*)(wi + WS_WBF));
    xconv_kernel<<<(N_NODES * 8 + 255) / 256, 256, 0, stream>>>(
        (const float4*)x, (ushort4*)(wi + WS_XSB));
    // 1. coarse per-chunk histograms, both dirs
    hist_kernel<<<NCHK, 512, 0, stream>>>(ei, wi + WS_CNTG);
    // 2. exclusive scan of the (dir,bin,chunk) count matrix
    scan_partial_kernel<<<SCAN_BLOCKS, 256, 0, stream>>>(
        (const int4*)(wi + WS_CNTG), wi + WS_BLKSUM, CNTG_N4);
    scan_blocksum_kernel<<<1, 256, 0, stream>>>(wi + WS_BLKSUM, SCAN_BLOCKS);
    scan_final_kernel<<<SCAN_BLOCKS, 256, 0, stream>>>(
        (int4*)(wi + WS_CNTG), wi + WS_BLKSUM, CNTG_N4);
    // 3. coalesced partition (one block per dir x 8192-chunk; LDS re-staging)
    partition_kernel<<<2 * NCHK, 512, 0, stream>>>(ei, ew, wi + WS_CNTG, binned);
    // 4. per-bin degrees + saved node counts (both dirs, linear stream)
    bindeg_kernel<<<2 * NBIN, 256, 0, stream>>>(
        wi + WS_CNTG, binned, wi + WS_BINCNT, wf);
    // 5. fused binsort+gather, both dirs -> bf16 Tx_o / Tx_i
    fgather_kernel<<<2 * NBIN, 256, 0, stream>>>(
        (const ushort4*)(wi + WS_XSB), wi + WS_CNTG, wi + WS_BINCNT, binned, wf);
    // 6. MFMA dense epilogue (bf16 Tx inputs)
    dense_kernel<<<DN_BLOCKS, 256, 0, stream>>>(
        (const float4*)x, (const int4*)(wi + WS_TXO), (const int4*)(wi + WS_TXI),
        (const unsigned short*)(wi + WS_WBF), bz, bh, Wlin, blin, out);
}

// Round 16
// 195.646 us; speedup vs baseline: 1.8906x; 1.0024x over previous
//
#include <hip/hip_runtime.h>
#include <math.h>

#define N_NODES 50000
#define N_EDGES 1600000
#define IN_CH 32
#define HID 64

// ---------------- pipeline (8 dispatches, zero global atomics) -------------
// prep(hist+wprep+xconv fused) -> scan(3) -> partition -> bindeg -> fgather
//   -> dense(MFMA)
// Round-16: (a) wprep/xconv/hist fused into one block-role-split kernel
// (hist blocks first: they feed the scan critical path) -- 2 fewer launch
// gaps; (b) dense stages x from the bf16 xsb copy (3.2 MB, L2-hot, raw int4
// copies) instead of fp32 x (12.8 MB + per-element converts). Bit-identical.
#define NBIN 782
#define BIN_SHIFT 6
#define CHUNK 8192
#define NCHK ((N_EDGES + CHUNK - 1) / CHUNK)   // 196
#define CNTG_N (2 * NBIN * NCHK)               // 306544 (divisible by 4)
#define CNTG_N4 (CNTG_N / 4)                   // 76636
#define SCAN_BLOCKS ((CNTG_N4 + 1023) / 1024)  // 75
#define FG_CAP 2560   // bin capacity: mean 2046 + ~11 sigma (Binomial)

#define PREP_WPREP_BLOCKS 48
#define PREP_XCONV_BLOCKS ((N_NODES * 8 + 255) / 256)  // 1563
#define PREP_BLOCKS (NCHK + PREP_WPREP_BLOCKS + PREP_XCONV_BLOCKS)  // 1807

// ---------------- workspace layout (int element offsets into d_ws)
#define WS_RDEG_OUT 0          // 50000 f (row-degree reciprocals, from dir1 bins)
#define WS_RDEG_IN  50000      // 50000 f (col-degree reciprocals, from dir0 bins)
#define WS_CNTG     100000     // 306544 i ((dir,bin,chunk) counts; scanned in place)
#define WS_BLKSUM   406548     // 128 i
#define WS_WBF      406676     // 6144 i = 12288 ushort (bf16 weights, B-frag order)
#define WS_BINCNT   412820     // 100096 i (1564 bins x 64 per-node counts)
#define WS_XSB      512916     // 800000 i = 1.6M ushort (bf16 x, unscaled)
#define WS_TXO      1312916    // 800000 i (bf16 Tx_o, 50000 x 32)
#define WS_TXI      2112916    // 800000 i (bf16 Tx_i)
#define WS_BINNED   2912916    // int2[3.2M] = 6400000 i
#define WS_END      9312916    // 37.3 MB (ws is 256 MiB)

typedef __attribute__((ext_vector_type(8))) short bf16x8;
typedef __attribute__((ext_vector_type(4))) float f32x4;

__device__ __forceinline__ unsigned short f2bf(float f) {  // RNE fp32 -> bf16
    unsigned int u = __float_as_uint(f);
    return (unsigned short)((u + 0x7fffu + ((u >> 16) & 1u)) >> 16);
}
__device__ __forceinline__ float bf2f(unsigned short b) {
    return __uint_as_float((unsigned int)b << 16);
}

// 0. fused prep: block-role split.
//   blocks [0, NCHK)           : per-chunk coarse histograms (both dirs)
//   blocks [NCHK, NCHK+48)     : weight prep (bf16, B-fragment order)
//   blocks [NCHK+48, PREP_BLOCKS): x -> bf16 copy
// B-frag order: idx = ((kk*8+bn)*64+lane)*8+j holds
// Bmat[k=kk*32+(lane>>4)*8+j][n=bn*16+(lane&15)], Bmat = [Wz_eff | Wh_eff].
__global__ __launch_bounds__(256) void prep_kernel(
    const int* __restrict__ ei, const float* __restrict__ Wz,
    const float* __restrict__ Wh, const float4* __restrict__ x4,
    int* __restrict__ cntG, unsigned short* __restrict__ wbf,
    ushort4* __restrict__ xsb) {
    __shared__ int h[2 * NBIN];
    int tid = threadIdx.x;
    int b = blockIdx.x;
    if (b < NCHK) {  // hist role
        for (int i = tid; i < 2 * NBIN; i += 256) h[i] = 0;
        __syncthreads();
        int e0 = b * CHUNK;
        int e1 = min(e0 + CHUNK, N_EDGES);
        for (int e = e0 + tid; e < e1; e += 256) {
            int r = ei[e];
            int c = ei[N_EDGES + e];
            atomicAdd(&h[c >> BIN_SHIFT], 1);           // dir0: group by col
            atomicAdd(&h[NBIN + (r >> BIN_SHIFT)], 1);  // dir1: group by row
        }
        __syncthreads();
        for (int i = tid; i < 2 * NBIN; i += 256) cntG[i * NCHK + b] = h[i];
    } else if (b < NCHK + PREP_WPREP_BLOCKS) {  // wprep role
        int idx = (b - NCHK) * 256 + tid;
        if (idx >= 12288) return;
        int j = idx & 7, ln = (idx >> 3) & 63, bn = (idx >> 9) & 7, kk = idx >> 12;
        int k = kk * 32 + (ln >> 4) * 8 + j;
        int n = bn * 16 + (ln & 15);
        int slab = k >> 5, c = k & 31;
        const float* W = (n < 64) ? Wz : Wh;
        int o = n & 63;
        float v;
        if (slab == 0)      v = W[c * 64 + o] + W[(2 * 96 + c) * 64 + o];
        else if (slab == 1) v = W[(96 + c) * 64 + o];
        else                v = W[(3 * 96 + c) * 64 + o];
        wbf[idx] = f2bf(v);
    } else {  // xconv role
        int i = (b - NCHK - PREP_WPREP_BLOCKS) * 256 + tid;
        if (i >= N_NODES * 8) return;
        float4 v = x4[i];
        ushort4 o;
        o.x = f2bf(v.x); o.y = f2bf(v.y); o.z = f2bf(v.z); o.w = f2bf(v.w);
        xsb[i] = o;
    }
}

// ---- 3-phase exclusive scan over cntG ----
__global__ __launch_bounds__(256) void scan_partial_kernel(
    const int4* __restrict__ cnt4, int* __restrict__ blksum, int n4) {
    __shared__ int s[256];
    int t = threadIdx.x;
    int base4 = blockIdx.x * 1024 + t * 4;
    int total = 0;
#pragma unroll
    for (int j = 0; j < 4; ++j) {
        int idx = base4 + j;
        if (idx < n4) {
            int4 v = cnt4[idx];
            total += v.x + v.y + v.z + v.w;
        }
    }
    s[t] = total;
    __syncthreads();
    for (int off = 128; off > 0; off >>= 1) {
        if (t < off) s[t] += s[t + off];
        __syncthreads();
    }
    if (t == 0) blksum[blockIdx.x] = s[0];
}

__global__ __launch_bounds__(256) void scan_blocksum_kernel(int* __restrict__ blksum, int nb) {
    __shared__ int s[256];
    int t = threadIdx.x;
    int v = (t < nb) ? blksum[t] : 0;
    s[t] = v;
    __syncthreads();
    for (int off = 1; off < 256; off <<= 1) {
        int u = (t >= off) ? s[t - off] : 0;
        __syncthreads();
        s[t] += u;
        __syncthreads();
    }
    if (t < nb) blksum[t] = s[t] - v;  // exclusive
}

__global__ __launch_bounds__(256) void scan_final_kernel(
    int4* __restrict__ cnt4, const int* __restrict__ blksum, int n4) {
    __shared__ int s[256];
    int t = threadIdx.x;
    int base4 = blockIdx.x * 1024 + t * 4;
    int4 vals[4];
    int total = 0;
#pragma unroll
    for (int j = 0; j < 4; ++j) {
        int idx = base4 + j;
        vals[j] = (idx < n4) ? cnt4[idx] : make_int4(0, 0, 0, 0);
        total += vals[j].x + vals[j].y + vals[j].z + vals[j].w;
    }
    s[t] = total;
    __syncthreads();
    for (int off = 1; off < 256; off <<= 1) {
        int u = (t >= off) ? s[t - off] : 0;
        __syncthreads();
        s[t] += u;
        __syncthreads();
    }
    int run = blksum[blockIdx.x] + s[t] - total;
#pragma unroll
    for (int j = 0; j < 4; ++j) {
        int idx = base4 + j;
        int4 v = vals[j];
        int4 o;
        o.x = run; run += v.x;
        o.y = run; run += v.y;
        o.z = run; run += v.z;
        o.w = run; run += v.w;
        if (idx < n4) cnt4[idx] = o;
    }
}

// 3. COALESCED partition. One block = one (dir, chunk of 8192); LDS
// re-staging makes the global write-out coalesced (runs ~10.4 edges).
__global__ __launch_bounds__(512) void partition_kernel(
    const int* __restrict__ ei, const float* __restrict__ ew,
    const int* __restrict__ cntG, int2* __restrict__ binned) {
    __shared__ int2 stg[CHUNK];      // 64 KB
    __shared__ int hist[NBIN];
    __shared__ int lst[NBIN];        // local bin starts
    __shared__ int gStart[NBIN];
    __shared__ int sc[512];
    int tid = threadIdx.x;
    int dir = (blockIdx.x >= NCHK) ? 1 : 0;
    int chunk = blockIdx.x - dir * NCHK;

    for (int i = tid; i < NBIN; i += 512) hist[i] = 0;
    __syncthreads();

    int e0 = chunk * CHUNK;
    int n_e = min(CHUNK, N_EDGES - e0);
    int binv[16], rankv[16];
    int2 pay[16];
#pragma unroll
    for (int j = 0; j < 16; ++j) {
        int idx = tid + j * 512;
        if (idx < n_e) {
            int e = e0 + idx;
            int r = ei[e];
            int c = ei[N_EDGES + e];
            int dst = dir ? r : c;
            int src = dir ? c : r;
            int b = dst >> BIN_SHIFT;
            binv[j] = b;
            rankv[j] = atomicAdd(&hist[b], 1);
            pay[j] = make_int2((int)(((unsigned)b << 22) | ((unsigned)(dst & 63) << 16) |
                                     (unsigned)src),
                               __float_as_int(ew[e]));
        } else {
            binv[j] = -1;
        }
    }
    __syncthreads();
    // pair-scan: 391 pairs cover 782 bins
    int ps = (tid < 391) ? (hist[2 * tid] + hist[2 * tid + 1]) : 0;
    sc[tid] = ps;
    __syncthreads();
    for (int off = 1; off < 512; off <<= 1) {
        int u = (tid >= off) ? sc[tid - off] : 0;
        __syncthreads();
        sc[tid] += u;
        __syncthreads();
    }
    if (tid < 391) {
        int pref = sc[tid] - ps;  // exclusive pair prefix
        lst[2 * tid] = pref;
        lst[2 * tid + 1] = pref + hist[2 * tid];
    }
    for (int i = tid; i < NBIN; i += 512)
        gStart[i] = cntG[(dir * NBIN + i) * NCHK + chunk];
    __syncthreads();
#pragma unroll
    for (int j = 0; j < 16; ++j)
        if (binv[j] >= 0) stg[lst[binv[j]] + rankv[j]] = pay[j];
    __syncthreads();
    for (int p = tid; p < n_e; p += 512) {
        int2 v2 = stg[p];
        int b = (int)(((unsigned)v2.x) >> 22);
        int gpos = gStart[b] + (p - lst[b]);
        binned[gpos] = make_int2(v2.x & 0x3FFFFF, v2.y);
    }
}

__device__ __forceinline__ void bin_range(const int* cntG, int b, int& lo, int& hi) {
    lo = cntG[b * NCHK];
    hi = (b + 1 < 2 * NBIN) ? cntG[(b + 1) * NCHK] : 2 * N_EDGES;
}

// 4. per-bin degrees + per-node counts (both dirs, one launch); linear stream.
__global__ __launch_bounds__(256) void bindeg_kernel(
    const int* __restrict__ cntG, const int2* __restrict__ binned,
    int* __restrict__ binCnt, float* __restrict__ ws_f) {
    __shared__ float wsum[64];
    __shared__ int cnt[64];
    int tid = threadIdx.x;
    int b = blockIdx.x;
    int dir = (b >= NBIN) ? 1 : 0;
    if (tid < 64) { wsum[tid] = 0.f; cnt[tid] = 0; }
    __syncthreads();
    int lo, hi;
    bin_range(cntG, b, lo, hi);
    for (int p = lo + tid; p < hi; p += 256) {
        int2 v = binned[p];
        int d = v.x >> 16;  // dstLocal (6 bits; bin bits stripped by partition)
        atomicAdd(&cnt[d], 1);
        atomicAdd(&wsum[d], __int_as_float(v.y));
    }
    __syncthreads();
    if (tid < 64) {
        binCnt[b * 64 + tid] = cnt[tid];
        int node = (b - dir * NBIN) * 64 + tid;
        if (node < N_NODES) {
            float s = wsum[tid];
            float* rdeg = ws_f + (dir == 0 ? WS_RDEG_IN : WS_RDEG_OUT);
            rdeg[node] = (s != 0.f) ? (1.f / s) : 0.f;
        }
    }
}

// 5. fused in-LDS binsort + register gather, both dirs, 256-thr blocks.
// B: coef = w*rdeg[src] computed here (off C's chain); s_edge = (src, coef).
// C: 32 groups x 8 lanes x 2 iterations, 4-way unrolled.
__global__ __launch_bounds__(256) void fgather_kernel(
    const ushort4* __restrict__ xsb, const int* __restrict__ cntG,
    const int* __restrict__ binCnt, const int2* __restrict__ binned,
    float* __restrict__ ws_f) {
    __shared__ int2 s_edge[FG_CAP];  // 20.5 KB -> 7 blocks/CU
    __shared__ int s_off[65];
    __shared__ int s_cur[64];
    __shared__ int sc[64];
    int tid = threadIdx.x;
    int b = blockIdx.x;
    int dir = (b >= NBIN) ? 1 : 0;
    int bin = b - dir * NBIN;

    // A: exclusive scan of 64 counts
    int v = (tid < 64) ? binCnt[b * 64 + tid] : 0;
    if (tid < 64) sc[tid] = v;
    __syncthreads();
    for (int off = 1; off < 64; off <<= 1) {
        int u = (tid < 64 && tid >= off) ? sc[tid - off] : 0;
        __syncthreads();
        if (tid < 64) sc[tid] += u;
        __syncthreads();
    }
    if (tid < 64) {
        s_off[tid] = sc[tid] - v;
        s_cur[tid] = sc[tid] - v;
    }
    if (tid == 63) s_off[64] = sc[63];
    __syncthreads();

    // B: stream bin edges; fold rdeg into coef; scatter (src, coef) sorted
    const float* rdeg = ws_f + (dir == 0 ? WS_RDEG_OUT : WS_RDEG_IN);
    int lo, hi;
    bin_range(cntG, b, lo, hi);
    int n_e = hi - lo;
    for (int p = tid; p < n_e; p += 256) {
        int2 ev = binned[lo + p];
        int src = ev.x & 0xffff;
        float coef = __int_as_float(ev.y) * rdeg[src];
        int rk = atomicAdd(&s_cur[ev.x >> 16], 1);
        if (rk < FG_CAP) s_edge[rk] = make_int2(src, __float_as_int(coef));
    }
    __syncthreads();

    // C: register-accumulating gather, 4-way unrolled
    ushort4* outp = (ushort4*)(ws_f + (dir == 0 ? WS_TXO : WS_TXI));
    int lane = tid & 7;
#pragma unroll
    for (int it = 0; it < 2; ++it) {
        int nl = it * 32 + (tid >> 3);
        int p = s_off[nl], end = s_off[nl + 1];
        float4 acc = make_float4(0.f, 0.f, 0.f, 0.f);
        for (; p + 3 < end; p += 4) {
            int2 v0 = s_edge[p], v1 = s_edge[p + 1];
            int2 v2 = s_edge[p + 2], v3 = s_edge[p + 3];
            ushort4 a0 = xsb[v0.x * 8 + lane];
            ushort4 a1 = xsb[v1.x * 8 + lane];
            ushort4 a2 = xsb[v2.x * 8 + lane];
            ushort4 a3 = xsb[v3.x * 8 + lane];
            float c0 = __int_as_float(v0.y), c1 = __int_as_float(v1.y);
            float c2 = __int_as_float(v2.y), c3 = __int_as_float(v3.y);
            acc.x += c0 * bf2f(a0.x) + c1 * bf2f(a1.x) + c2 * bf2f(a2.x) + c3 * bf2f(a3.x);
            acc.y += c0 * bf2f(a0.y) + c1 * bf2f(a1.y) + c2 * bf2f(a2.y) + c3 * bf2f(a3.y);
            acc.z += c0 * bf2f(a0.z) + c1 * bf2f(a1.z) + c2 * bf2f(a2.z) + c3 * bf2f(a3.z);
            acc.w += c0 * bf2f(a0.w) + c1 * bf2f(a1.w) + c2 * bf2f(a2.w) + c3 * bf2f(a3.w);
        }
        for (; p < end; ++p) {
            int2 v0 = s_edge[p];
            float c0 = __int_as_float(v0.y);
            ushort4 a = xsb[v0.x * 8 + lane];
            acc.x += c0 * bf2f(a.x);
            acc.y += c0 * bf2f(a.y);
            acc.z += c0 * bf2f(a.z);
            acc.w += c0 * bf2f(a.w);
        }
        int node = bin * 64 + nl;
        if (node < N_NODES) {
            ushort4 o;
            o.x = f2bf(acc.x); o.y = f2bf(acc.y);
            o.z = f2bf(acc.z); o.w = f2bf(acc.w);
            outp[node * 8 + lane] = o;
        }
    }
}

// 6. Dense epilogue via bf16 MFMA. Round-16: x staged from the bf16 xsb
// copy (raw int4, L2-hot) -- bit-identical to converting fp32 x here.
// Per block: C[64 x 128 (z|h)] = A[64x96]_bf16 x B[96x128]_bf16 + bias.
// A-frag: A[m=lane&15][k=quad*8+j]; B-frag: B[k=quad*8+j][n=lane&15];
// C/D: col=lane&15, row=quad*4+reg (m89/m91-verified).
#define DN_GROUP 64
#define DN_BLOCKS ((N_NODES + DN_GROUP - 1) / DN_GROUP)  // 782
__global__ __launch_bounds__(256) void dense_kernel(
    const int4* __restrict__ xsb4,
    const int4* __restrict__ txo_b, const int4* __restrict__ txi_b,
    const unsigned short* __restrict__ wbf,
    const float* __restrict__ bz, const float* __restrict__ bh,
    const float* __restrict__ Wlin, const float* __restrict__ blin,
    float* __restrict__ out) {
    __shared__ unsigned short sA[64 * 104];  // 13.0 KB
    __shared__ unsigned short sB[12288];     // 24.0 KB

    int tid = threadIdx.x;
    int lane = tid & 63, w = tid >> 6;
    int lm = lane & 15, quad = lane >> 4;

    for (int idx = tid; idx < 3072; idx += 256)
        *(ushort4*)&sB[idx * 4] = ((const ushort4*)wbf)[idx];

    int node0 = blockIdx.x * DN_GROUP;
    // x part: 64 nodes x 4 int4 (bf16, raw copy from xsb)
    for (int idx = tid; idx < 64 * 4; idx += 256) {
        int nl = idx >> 2, q = idx & 3;
        int node = node0 + nl;
        int4 v = (node < N_NODES) ? xsb4[node * 4 + q] : make_int4(0, 0, 0, 0);
        *(int4*)&sA[nl * 104 + q * 8] = v;
    }
    // Tx part: 64 nodes x (4+4) int4 raw bf16
    for (int idx = tid; idx < 64 * 8; idx += 256) {
        int nl = idx >> 3, q = idx & 7;
        int node = node0 + nl;
        int4 v = make_int4(0, 0, 0, 0);
        if (node < N_NODES)
            v = (q < 4) ? txo_b[node * 4 + q] : txi_b[node * 4 + (q - 4)];
        *(int4*)&sA[nl * 104 + 32 + q * 8] = v;
    }

    float bzv[4], bhv[4], wlv[4];
#pragma unroll
    for (int bn = 0; bn < 4; ++bn) {
        int o = lm + 16 * bn;
        bzv[bn] = bz[o]; bhv[bn] = bh[o]; wlv[bn] = Wlin[o];
    }
    float bl = blin[0];
    __syncthreads();

    f32x4 acc[8];
#pragma unroll
    for (int bn = 0; bn < 4; ++bn) {
        acc[bn]     = (f32x4){bzv[bn], bzv[bn], bzv[bn], bzv[bn]};
        acc[bn + 4] = (f32x4){bhv[bn], bhv[bn], bhv[bn], bhv[bn]};
    }
#pragma unroll
    for (int kk = 0; kk < 3; ++kk) {
        bf16x8 af = *(const bf16x8*)&sA[(w * 16 + lm) * 104 + kk * 32 + quad * 8];
#pragma unroll
        for (int bn = 0; bn < 8; ++bn) {
            bf16x8 bf = *(const bf16x8*)&sB[((kk * 8 + bn) * 64 + lane) * 8];
            acc[bn] = __builtin_amdgcn_mfma_f32_16x16x32_bf16(af, bf, acc[bn], 0, 0, 0);
        }
    }

    float partial[4] = {0.f, 0.f, 0.f, 0.f};
#pragma unroll
    for (int bn = 0; bn < 4; ++bn) {
#pragma unroll
        for (int reg = 0; reg < 4; ++reg) {
            float az = acc[bn][reg], ah = acc[bn + 4][reg];
            float z = 1.f / (1.f + __expf(-az));
            float ht = 1.f - 2.f / (__expf(2.f * ah) + 1.f);
            partial[reg] += fmaxf((1.f - z) * ht, 0.f) * wlv[bn];
        }
    }
#pragma unroll
    for (int reg = 0; reg < 4; ++reg) {
        float s = partial[reg];
        s += __shfl_xor(s, 1, 64);
        s += __shfl_xor(s, 2, 64);
        s += __shfl_xor(s, 4, 64);
        s += __shfl_xor(s, 8, 64);
        if (lm == 0) {
            int node = node0 + w * 16 + quad * 4 + reg;
            if (node < N_NODES) out[node] = s + bl;
        }
    }
}

extern "C" void kernel_launch(void* const* d_in, const int* in_sizes, int n_in,
                              void* d_out, int out_size, void* d_ws, size_t ws_size,
                              hipStream_t stream) {
    const float* x = (const float*)d_in[0];
    const int* ei = (const int*)d_in[1];
    const float* ew = (const float*)d_in[2];
    const float* Wz = (const float*)d_in[3];
    const float* bz = (const float*)d_in[4];
    // d_in[5]=Wr, d_in[6]=br dead: H0==0 makes the reset gate a no-op
    const float* Wh = (const float*)d_in[7];
    const float* bh = (const float*)d_in[8];
    const float* Wlin = (const float*)d_in[9];
    const float* blin = (const float*)d_in[10];
    float* out = (float*)d_out;
    float* wf = (float*)d_ws;
    int* wi = (int*)d_ws;
    int2* binned = (int2*)(wi + WS_BINNED);

    // 0. fused prep: hist (chunks, critical path) + wprep + xconv
    prep_kernel<<<PREP_BLOCKS, 256, 0, stream>>>(
        ei, Wz, Wh, (const float4*)x, wi + WS_CNTG,
        (unsigned short*)(wi + WS_WBF), (ushort4*)(wi + WS_XSB));
    // 1. exclusive scan of the (dir,bin,chunk) count matrix
    scan_partial_kernel<<<SCAN_BLOCKS, 256, 0, stream>>>(
        (const int4*)(wi + WS_CNTG), wi + WS_BLKSUM, CNTG_N4);
    scan_blocksum_kernel<<<1, 256, 0, stream>>>(wi + WS_BLKSUM, SCAN_BLOCKS);
    scan_final_kernel<<<SCAN_BLOCKS, 256, 0, stream>>>(
        (int4*)(wi + WS_CNTG), wi + WS_BLKSUM, CNTG_N4);
    // 2. coalesced partition (one block per dir x 8192-chunk; LDS re-staging)
    partition_kernel<<<2 * NCHK, 512, 0, stream>>>(ei, ew, wi + WS_CNTG, binned);
    // 3. per-bin degrees + saved node counts (both dirs, linear stream)
    bindeg_kernel<<<2 * NBIN, 256, 0, stream>>>(
        wi + WS_CNTG, binned, wi + WS_BINCNT, wf);
    // 4. fused binsort+gather, both dirs -> bf16 Tx_o / Tx_i
    fgather_kernel<<<2 * NBIN, 256, 0, stream>>>(
        (const ushort4*)(wi + WS_XSB), wi + WS_CNTG, wi + WS_BINCNT, binned, wf);
    // 5. MFMA dense epilogue (all-bf16 inputs)
    dense_kernel<<<DN_BLOCKS, 256, 0, stream>>>(
        (const int4*)(wi + WS_XSB), (const int4*)(wi + WS_TXO),
        (const int4*)(wi + WS_TXI), (const unsigned short*)(wi + WS_WBF),
        bz, bh, Wlin, blin, out);
}